// Round 8
// baseline (376.864 us; speedup 1.0000x reference)
//
#include <hip/hip_runtime.h>
#include <stdint.h>

#define NN 50000
#define EE 800000
#define DD 128
#define GG 16
#define CC 10
#define NBK 196                   // coarse buckets of 256 nodes: 196*256 = 50176 >= NN
#define BCH 4096                  // edges per sort block: 196*4096 = 802816 >= EE
#define SMAX 5120                 // max edges per bucket (mean 4096, wide margin)
#define FT (NBK * NBK)            // 38416 flat count entries
#define CHK 151                   // ceil(FT/256)

typedef unsigned short u16;
typedef __bf16 bf16x8 __attribute__((ext_vector_type(8)));
typedef float f32x4 __attribute__((ext_vector_type(4)));
typedef unsigned int u32x4 __attribute__((ext_vector_type(4)));
typedef float fl4 __attribute__((ext_vector_type(4)));

__device__ inline u16 f2bf(float f) {
    unsigned u = __float_as_uint(f);
    u = u + 0x7fffu + ((u >> 16) & 1u);   // RNE
    return (u16)(u >> 16);
}
__device__ inline unsigned pack2(float a, float b) {
    return (unsigned)f2bf(a) | ((unsigned)f2bf(b) << 16);
}
__device__ inline float bf2f(unsigned bits16) { return __uint_as_float(bits16 << 16); }
__device__ inline void acc8(float* a, uint4 v) {
    a[0] += __uint_as_float(v.x << 16); a[1] += __uint_as_float(v.x & 0xffff0000u);
    a[2] += __uint_as_float(v.y << 16); a[3] += __uint_as_float(v.y & 0xffff0000u);
    a[4] += __uint_as_float(v.z << 16); a[5] += __uint_as_float(v.z & 0xffff0000u);
    a[6] += __uint_as_float(v.w << 16); a[7] += __uint_as_float(v.w & 0xffff0000u);
}
__device__ inline void mand(uint4& v, int p) {     // zero the lane's contribution if !p
    unsigned m = p ? 0xffffffffu : 0u;
    v.x &= m; v.y &= m; v.z &= m; v.w &= m;
}
__device__ inline void nt_store16(void* p, uint4 v) {
    u32x4 x; x.x = v.x; x.y = v.y; x.z = v.z; x.w = v.w;
    __builtin_nontemporal_store(x, (u32x4*)p);
}
__device__ inline uint4 nt_load16(const void* p) {
    u32x4 x = __builtin_nontemporal_load((const u32x4*)p);
    uint4 r; r.x = x.x; r.y = x.y; r.z = x.z; r.w = x.w;
    return r;
}
__device__ inline float4 nt_loadf4(const float* p) {
    fl4 x = __builtin_nontemporal_load((const fl4*)p);
    float4 r; r.x = x.x; r.y = x.y; r.z = x.z; r.w = x.w;
    return r;
}

// ---------- fused prep + sortP1 ----------
// blocks 0..NBK-1: per-block LDS histogram over 196 coarse buckets, TRANSPOSED write.
// blocks NBK.. : zero pool, cvt h->bf16 (nt loads), transpose+cast weights.
#define PZ (GG * DD)                   // 2048 floats (pool) to zero
#define PC (NN * DD / 4)               // 1600000 float4 groups
#define PW (4 * DD * DD)               // 65536 weight elements
#define PTOT (PZ + PC + PW)
#define PBLK ((PTOT + 255) / 256)      // prep blocks

__global__ __launch_bounds__(256) void prepsort_kernel(
    const float* __restrict__ h,
    const float* __restrict__ a, const float* __restrict__ b,
    const float* __restrict__ c, const float* __restrict__ d,
    int* __restrict__ zbase, u16* __restrict__ H0, u16* __restrict__ wt,
    const int* __restrict__ dst, int* __restrict__ counts) {
    __shared__ int hist[NBK];
    int blk = blockIdx.x, t = threadIdx.x;
    if (blk < NBK) {                                 // ---- sortP1 part
        for (int i = t; i < NBK; i += 256) hist[i] = 0;
        __syncthreads();
        int e0 = blk * BCH, e1 = min(e0 + BCH, EE);
        for (int e = e0 + t; e < e1; e += 256) atomicAdd(&hist[dst[e] >> 8], 1);
        __syncthreads();
        for (int i = t; i < NBK; i += 256) counts[i * NBK + blk] = hist[i];  // transposed
        return;
    }
    // ---- prep part
    int i = (blk - NBK) * 256 + t;
    if (i < PZ) { zbase[i] = 0; return; }
    i -= PZ;
    if (i < PC) {
        int j = i * 4;
        float4 v = nt_loadf4(h + j);                 // h read once: don't pollute L2
        ushort4 o;
        o.x = f2bf(v.x); o.y = f2bf(v.y); o.z = f2bf(v.z); o.w = f2bf(v.w);
        *(ushort4*)(H0 + j) = o;
        return;
    }
    i -= PC;
    if (i < PW) {
        int m = i >> 14, r = i & 16383, k = r >> 7, j = r & 127;
        const float* W = (m == 0) ? a : (m == 1) ? b : (m == 2) ? c : d;
        wt[(m << 14) + (j << 7) + k] = f2bf(W[(k << 7) + j]);
    }
}

// ---------- sortP2 (1 block): flat exclusive scan of counts_T[FT]; also gstart ----------
// counts_T flat index (col j, block b) = j*NBK+b; exclusive scan over flat order
// = bucket base (cols j'<j) + per-col prefix (b'<b): exactly the write cursor.
__global__ __launch_bounds__(256) void sortP2_kernel(int* __restrict__ counts,
                                                     const int* __restrict__ gids,
                                                     int* __restrict__ gstart) {
    __shared__ int tmp[256];
    int t = threadIdx.x;
    if (t <= GG) {                                  // graph boundary binary search
        int lo = 0, hi = NN;
        while (lo < hi) { int mid = (lo + hi) >> 1; if (gids[mid] < t) lo = mid + 1; else hi = mid; }
        gstart[t] = lo;
    }
    int base = t * CHK;
    int s = 0;
    for (int i = 0; i < CHK; i++) {                 // pass 1: chunk sums (pipelined loads)
        int idx = base + i;
        if (idx < FT) s += counts[idx];
    }
    tmp[t] = s;
    __syncthreads();
    for (int off = 1; off < 256; off <<= 1) {       // inclusive scan of chunk sums
        int x = (t >= off) ? tmp[t - off] : 0;
        __syncthreads();
        tmp[t] += x;
        __syncthreads();
    }
    int pre = tmp[t] - s;                           // exclusive chunk prefix
    for (int i = 0; i < CHK; i++) {                 // pass 2: rewrite with running prefix
        int idx = base + i;
        if (idx < FT) { int cv = counts[idx]; counts[idx] = pre; pre += cv; }
    }
}

// ---------- sortP3: scatter packed (src<<8 | dst&255) into bucket regions ----------
__global__ __launch_bounds__(256) void sortP3_kernel(const int* __restrict__ src,
                                                     const int* __restrict__ dst,
                                                     const int* __restrict__ counts,
                                                     int* __restrict__ epack) {
    __shared__ int curs[NBK];
    int b = blockIdx.x, t = threadIdx.x;
    for (int i = t; i < NBK; i += 256) curs[i] = counts[i * NBK + b];   // transposed read
    __syncthreads();
    int e0 = b * BCH, e1 = min(e0 + BCH, EE);
    for (int e = e0 + t; e < e1; e += 256) {
        int dd = dst[e], s = src[e];
        int p = atomicAdd(&curs[dd >> 8], 1);
        epack[p] = (s << 8) | (dd & 255);           // src<2^16, local dst 8b -> 24b
    }
}

// ---------- sortP4 (1 block/bucket): local counting sort; offs + ssrc coalesced ----------
__global__ __launch_bounds__(256) void sortP4_kernel(const int* __restrict__ epack,
                                                     const int* __restrict__ counts,
                                                     int* __restrict__ offs,
                                                     int* __restrict__ ssrc) {
    __shared__ int hist[256];
    __shared__ int curs[256];
    __shared__ int stage[SMAX];
    int j = blockIdx.x, t = threadIdx.x;
    int n0 = j << 8;
    int b0 = counts[j * NBK];                       // bucket base = flat scan at (j,0)
    int b1 = (j < NBK - 1) ? counts[(j + 1) * NBK] : EE;
    hist[t] = 0;
    __syncthreads();
    for (int e = b0 + t; e < b1; e += 256) atomicAdd(&hist[epack[e] & 255], 1);
    __syncthreads();
    int deg = hist[t];
    for (int off = 1; off < 256; off <<= 1) {       // inclusive scan
        int x = (t >= off) ? hist[t - off] : 0;
        __syncthreads();
        hist[t] += x;
        __syncthreads();
    }
    int loff = hist[t] - deg;                       // exclusive local offset
    curs[t] = loff;
    if (n0 + t <= NN) offs[n0 + t] = b0 + loff;     // block 195/t=80 writes offs[NN]=EE
    __syncthreads();
    for (int e = b0 + t; e < b1; e += 256) {
        int pk = epack[e];
        int p = atomicAdd(&curs[pk & 255], 1);
        stage[p] = pk >> 8;                         // src
    }
    __syncthreads();
    int n = b1 - b0;
    for (int i = t; i < n; i += 256) ssrc[b0 + i] = stage[i];   // coalesced
}

// ---------- aggregation: z = h + sum_{incoming} h_src ----------
// work item = (node, 128B half-row); 8 lanes per item, 8 items per wave.
// ceil(deg/8) chunks of 8 predicated loads, next-chunk index prefetch, no tail.
__global__ __launch_bounds__(256) void agg_kernel(
    const u16* __restrict__ Hin, const int* __restrict__ offs,
    const int* __restrict__ ssrc, u16* __restrict__ Z) {
    int gid = blockIdx.x * 32 + (threadIdx.x >> 3);   // 0..99999
    int lid = threadIdx.x & 7;
    if (gid >= 2 * NN) return;
    int node = gid >> 1;
    int foff = (gid & 1) * 64 + lid * 8;              // 16B slice
    const u16* base = Hin + foff;

    float acc[8] = {0.f, 0.f, 0.f, 0.f, 0.f, 0.f, 0.f, 0.f};
    uint4 vs = *(const uint4*)(base + (size_t)node * DD);
    int e0 = offs[node], e1 = offs[node + 1];
    acc8(acc, vs);                                    // self term (eps=0)

    int nch = (e1 - e0 + 7) >> 3;
    if (nch > 0) {
        int elast = e1 - 1;
        int i0 = ssrc[e0];
        int i1 = ssrc[min(e0 + 1, elast)];
        int i2 = ssrc[min(e0 + 2, elast)];
        int i3 = ssrc[min(e0 + 3, elast)];
        int i4 = ssrc[min(e0 + 4, elast)];
        int i5 = ssrc[min(e0 + 5, elast)];
        int i6 = ssrc[min(e0 + 6, elast)];
        int i7 = ssrc[min(e0 + 7, elast)];
        int eb = e0;
        for (int c = 0; c < nch; c++) {
            int ebn = eb + 8;
            int n0 = i0, n1 = i1, n2 = i2, n3 = i3, n4 = i4, n5 = i5, n6 = i6, n7 = i7;
            if (c + 1 < nch) {                         // prefetch next chunk indices
                n0 = ssrc[ebn];
                n1 = ssrc[min(ebn + 1, elast)];
                n2 = ssrc[min(ebn + 2, elast)];
                n3 = ssrc[min(ebn + 3, elast)];
                n4 = ssrc[min(ebn + 4, elast)];
                n5 = ssrc[min(ebn + 5, elast)];
                n6 = ssrc[min(ebn + 6, elast)];
                n7 = ssrc[min(ebn + 7, elast)];
            }
            uint4 v0 = *(const uint4*)(base + (size_t)i0 * DD);
            uint4 v1 = *(const uint4*)(base + (size_t)i1 * DD);
            uint4 v2 = *(const uint4*)(base + (size_t)i2 * DD);
            uint4 v3 = *(const uint4*)(base + (size_t)i3 * DD);
            uint4 v4 = *(const uint4*)(base + (size_t)i4 * DD);
            uint4 v5 = *(const uint4*)(base + (size_t)i5 * DD);
            uint4 v6 = *(const uint4*)(base + (size_t)i6 * DD);
            uint4 v7 = *(const uint4*)(base + (size_t)i7 * DD);
            mand(v1, eb + 1 < e1); mand(v2, eb + 2 < e1); mand(v3, eb + 3 < e1);
            mand(v4, eb + 4 < e1); mand(v5, eb + 5 < e1); mand(v6, eb + 6 < e1);
            mand(v7, eb + 7 < e1);                     // slot 0 always valid
            acc8(acc, v0); acc8(acc, v1); acc8(acc, v2); acc8(acc, v3);
            acc8(acc, v4); acc8(acc, v5); acc8(acc, v6); acc8(acc, v7);
            i0 = n0; i1 = n1; i2 = n2; i3 = n3; i4 = n4; i5 = n5; i6 = n6; i7 = n7;
            eb = ebn;
        }
    }
    uint4 o;
    o.x = pack2(acc[0], acc[1]); o.y = pack2(acc[2], acc[3]);
    o.z = pack2(acc[4], acc[5]); o.w = pack2(acc[6], acc[7]);
    nt_store16(Z + (size_t)node * DD + foff, o);      // stream-once: keep L2 for gathers
}

// ---------- MLP: out = relu(relu(z@W1+b1)@W2+b2) ----------
// block 256 = 4 waves; wave owns 16 rows; wave-private (no barriers).
__global__ __launch_bounds__(256) void mlp_kernel(
    const u16* __restrict__ Zin, const u16* __restrict__ Wt1, const float* __restrict__ b1,
    const u16* __restrict__ Wt2, const float* __restrict__ b2,
    u16* __restrict__ Hout) {
    __shared__ u16 zb[64][136];   // row stride 272B: 16B-aligned, wave-private 16-row tiles
    const int wave = threadIdx.x >> 6;
    const int lane = threadIdx.x & 63;
    const int m16 = lane & 15;
    const int quad = lane >> 4;
    const int row0 = blockIdx.x * 64 + wave * 16;

    // stage 16 rows x 256B, fully coalesced (1KB per instruction); z is read-once
#pragma unroll
    for (int p = 0; p < 4; p++) {
        int idx = p * 64 + lane;          // 0..255 16B-chunks
        int r = idx >> 4, ch = idx & 15;
        if (row0 + r < NN) {
            uint4 v = nt_load16(Zin + (size_t)(row0 + r) * DD + ch * 8);
            *(uint4*)&zb[wave * 16 + r][ch * 8] = v;
        }
    }

    // ---- GEMM1
    bf16x8 afr[4];
#pragma unroll
    for (int kk = 0; kk < 4; kk++)
        afr[kk] = *(const bf16x8*)&zb[wave * 16 + m16][kk * 32 + quad * 8];
    f32x4 acc[8];
#pragma unroll
    for (int nt = 0; nt < 8; nt++) acc[nt] = (f32x4){0.f, 0.f, 0.f, 0.f};
#pragma unroll
    for (int kk = 0; kk < 4; kk++) {
#pragma unroll
        for (int nt = 0; nt < 8; nt++) {
            bf16x8 bfr = *(const bf16x8*)(Wt1 + ((nt * 16 + m16) << 7) + kk * 32 + quad * 8);
            acc[nt] = __builtin_amdgcn_mfma_f32_16x16x32_bf16(afr[kk], bfr, acc[nt], 0, 0, 0);
        }
    }
#pragma unroll
    for (int nt = 0; nt < 8; nt++) {      // y -> zb (zb dead after afr read; wave-private)
        int col = nt * 16 + m16;
        float bias = b1[col];
#pragma unroll
        for (int r = 0; r < 4; r++) {
            float yv = acc[nt][r] + bias;
            yv = yv > 0.f ? yv : 0.f;
            zb[wave * 16 + quad * 4 + r][col] = f2bf(yv);
        }
    }

    // ---- GEMM2
#pragma unroll
    for (int kk = 0; kk < 4; kk++)
        afr[kk] = *(const bf16x8*)&zb[wave * 16 + m16][kk * 32 + quad * 8];
#pragma unroll
    for (int nt = 0; nt < 8; nt++) acc[nt] = (f32x4){0.f, 0.f, 0.f, 0.f};
#pragma unroll
    for (int kk = 0; kk < 4; kk++) {
#pragma unroll
        for (int nt = 0; nt < 8; nt++) {
            bf16x8 bfr = *(const bf16x8*)(Wt2 + ((nt * 16 + m16) << 7) + kk * 32 + quad * 8);
            acc[nt] = __builtin_amdgcn_mfma_f32_16x16x32_bf16(afr[kk], bfr, acc[nt], 0, 0, 0);
        }
    }
#pragma unroll
    for (int nt = 0; nt < 8; nt++) {      // stage output in zb, then coalesced store
        int col = nt * 16 + m16;
        float bias = b2[col];
#pragma unroll
        for (int r = 0; r < 4; r++) {
            float ov = acc[nt][r] + bias;
            ov = ov > 0.f ? ov : 0.f;
            zb[wave * 16 + quad * 4 + r][col] = f2bf(ov);
        }
    }
#pragma unroll
    for (int p = 0; p < 4; p++) {
        int idx = p * 64 + lane;
        int r = idx >> 4, ch = idx & 15;
        if (row0 + r < NN)
            nt_store16(Hout + (size_t)(row0 + r) * DD + ch * 8, *(const uint4*)&zb[wave * 16 + r][ch * 8]);
    }
}

// ---------- mean-pool partial sums ----------
__global__ void pool_kernel(const u16* __restrict__ H2, const int* __restrict__ gstart,
                            float* __restrict__ pool) {
    int g = blockIdx.x >> 5, q = blockIdx.x & 31;
    int f = threadIdx.x;   // 0..127
    int s = gstart[g], e = gstart[g + 1];
    float sum = 0.f;
    for (int n = s + q; n < e; n += 32) sum += bf2f(H2[(size_t)n * DD + f]);
    atomicAdd(&pool[g * DD + f], sum);
}

// ---------- classifier (fp32) ----------
__global__ void cls_kernel(const float* __restrict__ pool, const int* __restrict__ gstart,
                           const float* __restrict__ Wc1, const float* __restrict__ bc1,
                           const float* __restrict__ Wc2, const float* __restrict__ bc2,
                           float* __restrict__ out) {
    __shared__ float hg[128];
    __shared__ float y1[128];
    int g = blockIdx.x;
    int t = threadIdx.x;   // 128 threads
    int cnt = gstart[g + 1] - gstart[g];
    float inv = 1.f / (float)(cnt > 1 ? cnt : 1);
    hg[t] = pool[g * DD + t] * inv;
    __syncthreads();
    float a = bc1[t];
    for (int k = 0; k < DD; k++) a += hg[k] * Wc1[k * DD + t];
    y1[t] = a > 0.f ? a : 0.f;
    __syncthreads();
    if (t < CC) {
        float o = bc2[t];
        for (int k = 0; k < DD; k++) o += y1[k] * Wc2[k * CC + t];
        out[g * CC + t] = o;
    }
}

extern "C" void kernel_launch(void* const* d_in, const int* in_sizes, int n_in,
                              void* d_out, int out_size, void* d_ws, size_t ws_size,
                              hipStream_t stream) {
    const float* h    = (const float*)d_in[0];
    const int*   src  = (const int*)d_in[1];
    const int*   dst  = (const int*)d_in[2];
    const int*   gids = (const int*)d_in[3];
    const float* W1a  = (const float*)d_in[4];
    const float* b1a  = (const float*)d_in[5];
    const float* W2a  = (const float*)d_in[6];
    const float* b2a  = (const float*)d_in[7];
    const float* W1b  = (const float*)d_in[8];
    const float* b1b  = (const float*)d_in[9];
    const float* W2b  = (const float*)d_in[10];
    const float* b2b  = (const float*)d_in[11];
    const float* Wc1  = (const float*)d_in[12];
    const float* bc1  = (const float*)d_in[13];
    const float* Wc2  = (const float*)d_in[14];
    const float* bc2  = (const float*)d_in[15];
    float* out = (float*)d_out;

    char* ws = (char*)d_ws;
    u16*   H0     = (u16*)(ws);                    // 12,800,000 B
    u16*   H1     = (u16*)(ws + 12800000);         // 12,800,000 B
    u16*   H2     = (u16*)(ws + 25600000);         // 12,800,000 B
    u16*   Wt     = (u16*)(ws + 38400000);         // 131,072 B
    float* pool   = (float*)(ws + 38531072);       // 8,192 B (zeroed by prep)
    int*   offs   = (int*)(ws + 38539264);         // 200,004 B
    int*   ssrc   = (int*)(ws + 38739268);         // 3,200,000 B
    int*   gstart = (int*)(ws + 41939268);         // 68 B
    int*   counts = (int*)(ws + 41939336);         // 153,664 B (196x196, transposed)
    int*   epack  = (int*)(ws + 42093792);         // 3,200,000 B (packed src|dstlocal)
    u16*   Z1     = H2;                            // scratch z, layer 1 (H2 written later by mlp2)
    u16*   Z2     = H0;                            // scratch z, layer 2 (H0 dead after agg1)

    prepsort_kernel<<<dim3(NBK + PBLK), dim3(256), 0, stream>>>(
        h, W1a, W2a, W1b, W2b, (int*)pool, H0, Wt, dst, counts);
    sortP2_kernel<<<dim3(1), dim3(256), 0, stream>>>(counts, gids, gstart);
    sortP3_kernel<<<dim3(NBK), dim3(256), 0, stream>>>(src, dst, counts, epack);
    sortP4_kernel<<<dim3(NBK), dim3(256), 0, stream>>>(epack, counts, offs, ssrc);
    agg_kernel<<<dim3((2 * NN + 31) / 32), dim3(256), 0, stream>>>(H0, offs, ssrc, Z1);
    mlp_kernel<<<dim3((NN + 63) / 64), dim3(256), 0, stream>>>(Z1, Wt, b1a, Wt + 16384, b2a, H1);
    agg_kernel<<<dim3((2 * NN + 31) / 32), dim3(256), 0, stream>>>(H1, offs, ssrc, Z2);
    mlp_kernel<<<dim3((NN + 63) / 64), dim3(256), 0, stream>>>(Z2, Wt + 32768, b1b, Wt + 49152, b2b, H2);
    pool_kernel<<<dim3(GG * 32), dim3(128), 0, stream>>>(H2, gstart, pool);
    cls_kernel<<<dim3(GG), dim3(128), 0, stream>>>(pool, gstart, Wc1, bc1, Wc2, bc2, out);
}

// Round 9
// 302.852 us; speedup vs baseline: 1.2444x; 1.2444x over previous
//
#include <hip/hip_runtime.h>
#include <stdint.h>

#define NN 50000
#define EE 800000
#define DD 128
#define GG 16
#define CC 10
#define NBK 196                   // coarse buckets of 256 nodes: 196*256 = 50176 >= NN
#define BCH 4096                  // edges per sort block: 196*4096 = 802816 >= EE
#define SMAX 5120                 // max edges per bucket (mean 4096, wide margin)
#define FT (NBK * NBK)            // 38416 flat count entries
#define NSCN ((FT + 255) / 256)   // 151 scan blocks

typedef unsigned short u16;
typedef __bf16 bf16x8 __attribute__((ext_vector_type(8)));
typedef float f32x4 __attribute__((ext_vector_type(4)));
typedef unsigned int u32x4 __attribute__((ext_vector_type(4)));
typedef float fl4 __attribute__((ext_vector_type(4)));

__device__ inline u16 f2bf(float f) {
    unsigned u = __float_as_uint(f);
    u = u + 0x7fffu + ((u >> 16) & 1u);   // RNE
    return (u16)(u >> 16);
}
__device__ inline unsigned pack2(float a, float b) {
    return (unsigned)f2bf(a) | ((unsigned)f2bf(b) << 16);
}
__device__ inline float bf2f(unsigned bits16) { return __uint_as_float(bits16 << 16); }
__device__ inline void acc8(float* a, uint4 v) {
    a[0] += __uint_as_float(v.x << 16); a[1] += __uint_as_float(v.x & 0xffff0000u);
    a[2] += __uint_as_float(v.y << 16); a[3] += __uint_as_float(v.y & 0xffff0000u);
    a[4] += __uint_as_float(v.z << 16); a[5] += __uint_as_float(v.z & 0xffff0000u);
    a[6] += __uint_as_float(v.w << 16); a[7] += __uint_as_float(v.w & 0xffff0000u);
}
__device__ inline void mand(uint4& v, int p) {     // zero the lane's contribution if !p
    unsigned m = p ? 0xffffffffu : 0u;
    v.x &= m; v.y &= m; v.z &= m; v.w &= m;
}
__device__ inline void nt_store16(void* p, uint4 v) {
    u32x4 x; x.x = v.x; x.y = v.y; x.z = v.z; x.w = v.w;
    __builtin_nontemporal_store(x, (u32x4*)p);
}
__device__ inline uint4 nt_load16(const void* p) {
    u32x4 x = __builtin_nontemporal_load((const u32x4*)p);
    uint4 r; r.x = x.x; r.y = x.y; r.z = x.z; r.w = x.w;
    return r;
}
__device__ inline float4 nt_loadf4(const float* p) {
    fl4 x = __builtin_nontemporal_load((const fl4*)p);
    float4 r; r.x = x.x; r.y = x.y; r.z = x.z; r.w = x.w;
    return r;
}

// ---------- fused prep + sortP1 ----------
// blocks 0..NBK-1: per-block LDS histogram over 196 coarse buckets, TRANSPOSED write.
// blocks NBK.. : zero pool, cvt h->bf16 (nt loads), transpose+cast weights.
#define PZ (GG * DD)                   // 2048 floats (pool) to zero
#define PC (NN * DD / 4)               // 1600000 float4 groups
#define PW (4 * DD * DD)               // 65536 weight elements
#define PTOT (PZ + PC + PW)
#define PBLK ((PTOT + 255) / 256)      // prep blocks

__global__ __launch_bounds__(256) void prepsort_kernel(
    const float* __restrict__ h,
    const float* __restrict__ a, const float* __restrict__ b,
    const float* __restrict__ c, const float* __restrict__ d,
    int* __restrict__ zbase, u16* __restrict__ H0, u16* __restrict__ wt,
    const int* __restrict__ dst, int* __restrict__ counts) {
    __shared__ int hist[NBK];
    int blk = blockIdx.x, t = threadIdx.x;
    if (blk < NBK) {                                 // ---- sortP1 part
        for (int i = t; i < NBK; i += 256) hist[i] = 0;
        __syncthreads();
        int e0 = blk * BCH, e1 = min(e0 + BCH, EE);
        for (int e = e0 + t; e < e1; e += 256) atomicAdd(&hist[dst[e] >> 8], 1);
        __syncthreads();
        for (int i = t; i < NBK; i += 256) counts[i * NBK + blk] = hist[i];  // transposed
        return;
    }
    // ---- prep part
    int i = (blk - NBK) * 256 + t;
    if (i < PZ) { zbase[i] = 0; return; }
    i -= PZ;
    if (i < PC) {
        int j = i * 4;
        float4 v = nt_loadf4(h + j);                 // h read once: don't pollute L2
        ushort4 o;
        o.x = f2bf(v.x); o.y = f2bf(v.y); o.z = f2bf(v.z); o.w = f2bf(v.w);
        *(ushort4*)(H0 + j) = o;
        return;
    }
    i -= PC;
    if (i < PW) {
        int m = i >> 14, r = i & 16383, k = r >> 7, j = r & 127;
        const float* W = (m == 0) ? a : (m == 1) ? b : (m == 2) ? c : d;
        wt[(m << 14) + (j << 7) + k] = f2bf(W[(k << 7) + j]);
    }
}

// ---------- parallel flat exclusive scan of counts_T[FT] (3-phase) ----------
// Flat scan over (col j, block b)=j*NBK+b gives bucket base + per-col prefix
// = exactly the sortP3 write cursor; counts[j*NBK] = bucket base for sortP4.
__global__ __launch_bounds__(256) void scanA_kernel(int* __restrict__ counts,
                                                    int* __restrict__ bsum) {
    __shared__ int tmp[256];
    int t = threadIdx.x, idx = blockIdx.x * 256 + t;
    int v = (idx < FT) ? counts[idx] : 0;
    tmp[t] = v; __syncthreads();
    for (int off = 1; off < 256; off <<= 1) {
        int x = (t >= off) ? tmp[t - off] : 0;
        __syncthreads();
        tmp[t] += x;
        __syncthreads();
    }
    if (idx < FT) counts[idx] = tmp[t] - v;          // exclusive within block
    if (t == 255) bsum[blockIdx.x] = tmp[255];
}

__global__ __launch_bounds__(256) void scanB_kernel(int* __restrict__ bsum,
                                                    const int* __restrict__ gids,
                                                    int* __restrict__ gstart) {
    __shared__ int tmp[256];
    int t = threadIdx.x;
    if (t <= GG) {                                  // graph boundary binary search
        int lo = 0, hi = NN;
        while (lo < hi) { int mid = (lo + hi) >> 1; if (gids[mid] < t) lo = mid + 1; else hi = mid; }
        gstart[t] = lo;
    }
    int v = (t < NSCN) ? bsum[t] : 0;
    tmp[t] = v; __syncthreads();
    for (int off = 1; off < 256; off <<= 1) {
        int x = (t >= off) ? tmp[t - off] : 0;
        __syncthreads();
        tmp[t] += x;
        __syncthreads();
    }
    if (t < NSCN) bsum[t] = tmp[t] - v;              // exclusive block offsets
}

__global__ __launch_bounds__(256) void scanC_kernel(int* __restrict__ counts,
                                                    const int* __restrict__ bsum) {
    int idx = blockIdx.x * 256 + threadIdx.x;
    if (idx < FT) counts[idx] += bsum[blockIdx.x];
}

// ---------- sortP3: scatter packed (src<<8 | dst&255) into bucket regions ----------
__global__ __launch_bounds__(256) void sortP3_kernel(const int* __restrict__ src,
                                                     const int* __restrict__ dst,
                                                     const int* __restrict__ counts,
                                                     int* __restrict__ epack) {
    __shared__ int curs[NBK];
    int b = blockIdx.x, t = threadIdx.x;
    for (int i = t; i < NBK; i += 256) curs[i] = counts[i * NBK + b];   // transposed read
    __syncthreads();
    int e0 = b * BCH, e1 = min(e0 + BCH, EE);
    for (int e = e0 + t; e < e1; e += 256) {
        int dd = dst[e], s = src[e];
        int p = atomicAdd(&curs[dd >> 8], 1);
        epack[p] = (s << 8) | (dd & 255);           // src<2^16, local dst 8b -> 24b
    }
}

// ---------- sortP4 (1 block/bucket): local counting sort; offs + ssrc coalesced ----------
__global__ __launch_bounds__(256) void sortP4_kernel(const int* __restrict__ epack,
                                                     const int* __restrict__ counts,
                                                     int* __restrict__ offs,
                                                     int* __restrict__ ssrc) {
    __shared__ int hist[256];
    __shared__ int curs[256];
    __shared__ int stage[SMAX];
    int j = blockIdx.x, t = threadIdx.x;
    int n0 = j << 8;
    int b0 = counts[j * NBK];                       // bucket base = flat scan at (j,0)
    int b1 = (j < NBK - 1) ? counts[(j + 1) * NBK] : EE;
    hist[t] = 0;
    __syncthreads();
    for (int e = b0 + t; e < b1; e += 256) atomicAdd(&hist[epack[e] & 255], 1);
    __syncthreads();
    int deg = hist[t];
    for (int off = 1; off < 256; off <<= 1) {       // inclusive scan
        int x = (t >= off) ? hist[t - off] : 0;
        __syncthreads();
        hist[t] += x;
        __syncthreads();
    }
    int loff = hist[t] - deg;                       // exclusive local offset
    curs[t] = loff;
    if (n0 + t <= NN) offs[n0 + t] = b0 + loff;     // block 195/t=80 writes offs[NN]=EE
    __syncthreads();
    for (int e = b0 + t; e < b1; e += 256) {
        int pk = epack[e];
        int p = atomicAdd(&curs[pk & 255], 1);
        stage[p] = pk >> 8;                         // src
    }
    __syncthreads();
    int n = b1 - b0;
    for (int i = t; i < n; i += 256) ssrc[b0 + i] = stage[i];   // coalesced
}

// ---------- aggregation: z = h + sum_{incoming} h_src ----------
// work item = (node, 128B half-row); 8 lanes per item, 8 items per wave.
// ceil(deg/8) chunks of 8 predicated loads, next-chunk index prefetch, no tail.
__global__ __launch_bounds__(256) void agg_kernel(
    const u16* __restrict__ Hin, const int* __restrict__ offs,
    const int* __restrict__ ssrc, u16* __restrict__ Z) {
    int gid = blockIdx.x * 32 + (threadIdx.x >> 3);   // 0..99999
    int lid = threadIdx.x & 7;
    if (gid >= 2 * NN) return;
    int node = gid >> 1;
    int foff = (gid & 1) * 64 + lid * 8;              // 16B slice
    const u16* base = Hin + foff;

    float acc[8] = {0.f, 0.f, 0.f, 0.f, 0.f, 0.f, 0.f, 0.f};
    uint4 vs = *(const uint4*)(base + (size_t)node * DD);
    int e0 = offs[node], e1 = offs[node + 1];
    acc8(acc, vs);                                    // self term (eps=0)

    int nch = (e1 - e0 + 7) >> 3;
    if (nch > 0) {
        int elast = e1 - 1;
        int i0 = ssrc[e0];
        int i1 = ssrc[min(e0 + 1, elast)];
        int i2 = ssrc[min(e0 + 2, elast)];
        int i3 = ssrc[min(e0 + 3, elast)];
        int i4 = ssrc[min(e0 + 4, elast)];
        int i5 = ssrc[min(e0 + 5, elast)];
        int i6 = ssrc[min(e0 + 6, elast)];
        int i7 = ssrc[min(e0 + 7, elast)];
        int eb = e0;
        for (int c = 0; c < nch; c++) {
            int ebn = eb + 8;
            int n0 = i0, n1 = i1, n2 = i2, n3 = i3, n4 = i4, n5 = i5, n6 = i6, n7 = i7;
            if (c + 1 < nch) {                         // prefetch next chunk indices
                n0 = ssrc[ebn];
                n1 = ssrc[min(ebn + 1, elast)];
                n2 = ssrc[min(ebn + 2, elast)];
                n3 = ssrc[min(ebn + 3, elast)];
                n4 = ssrc[min(ebn + 4, elast)];
                n5 = ssrc[min(ebn + 5, elast)];
                n6 = ssrc[min(ebn + 6, elast)];
                n7 = ssrc[min(ebn + 7, elast)];
            }
            uint4 v0 = *(const uint4*)(base + (size_t)i0 * DD);
            uint4 v1 = *(const uint4*)(base + (size_t)i1 * DD);
            uint4 v2 = *(const uint4*)(base + (size_t)i2 * DD);
            uint4 v3 = *(const uint4*)(base + (size_t)i3 * DD);
            uint4 v4 = *(const uint4*)(base + (size_t)i4 * DD);
            uint4 v5 = *(const uint4*)(base + (size_t)i5 * DD);
            uint4 v6 = *(const uint4*)(base + (size_t)i6 * DD);
            uint4 v7 = *(const uint4*)(base + (size_t)i7 * DD);
            mand(v1, eb + 1 < e1); mand(v2, eb + 2 < e1); mand(v3, eb + 3 < e1);
            mand(v4, eb + 4 < e1); mand(v5, eb + 5 < e1); mand(v6, eb + 6 < e1);
            mand(v7, eb + 7 < e1);                     // slot 0 always valid
            acc8(acc, v0); acc8(acc, v1); acc8(acc, v2); acc8(acc, v3);
            acc8(acc, v4); acc8(acc, v5); acc8(acc, v6); acc8(acc, v7);
            i0 = n0; i1 = n1; i2 = n2; i3 = n3; i4 = n4; i5 = n5; i6 = n6; i7 = n7;
            eb = ebn;
        }
    }
    uint4 o;
    o.x = pack2(acc[0], acc[1]); o.y = pack2(acc[2], acc[3]);
    o.z = pack2(acc[4], acc[5]); o.w = pack2(acc[6], acc[7]);
    nt_store16(Z + (size_t)node * DD + foff, o);      // stream-once: keep L2 for gathers
}

// ---------- MLP: out = relu(relu(z@W1+b1)@W2+b2) ----------
// block 256 = 4 waves; wave owns 16 rows; wave-private (no barriers).
__global__ __launch_bounds__(256) void mlp_kernel(
    const u16* __restrict__ Zin, const u16* __restrict__ Wt1, const float* __restrict__ b1,
    const u16* __restrict__ Wt2, const float* __restrict__ b2,
    u16* __restrict__ Hout) {
    __shared__ u16 zb[64][136];   // row stride 272B: 16B-aligned, wave-private 16-row tiles
    const int wave = threadIdx.x >> 6;
    const int lane = threadIdx.x & 63;
    const int m16 = lane & 15;
    const int quad = lane >> 4;
    const int row0 = blockIdx.x * 64 + wave * 16;

    // stage 16 rows x 256B, fully coalesced (1KB per instruction); z is read-once
#pragma unroll
    for (int p = 0; p < 4; p++) {
        int idx = p * 64 + lane;          // 0..255 16B-chunks
        int r = idx >> 4, ch = idx & 15;
        if (row0 + r < NN) {
            uint4 v = nt_load16(Zin + (size_t)(row0 + r) * DD + ch * 8);
            *(uint4*)&zb[wave * 16 + r][ch * 8] = v;
        }
    }

    // ---- GEMM1
    bf16x8 afr[4];
#pragma unroll
    for (int kk = 0; kk < 4; kk++)
        afr[kk] = *(const bf16x8*)&zb[wave * 16 + m16][kk * 32 + quad * 8];
    f32x4 acc[8];
#pragma unroll
    for (int nt = 0; nt < 8; nt++) acc[nt] = (f32x4){0.f, 0.f, 0.f, 0.f};
#pragma unroll
    for (int kk = 0; kk < 4; kk++) {
#pragma unroll
        for (int nt = 0; nt < 8; nt++) {
            bf16x8 bfr = *(const bf16x8*)(Wt1 + ((nt * 16 + m16) << 7) + kk * 32 + quad * 8);
            acc[nt] = __builtin_amdgcn_mfma_f32_16x16x32_bf16(afr[kk], bfr, acc[nt], 0, 0, 0);
        }
    }
#pragma unroll
    for (int nt = 0; nt < 8; nt++) {      // y -> zb (zb dead after afr read; wave-private)
        int col = nt * 16 + m16;
        float bias = b1[col];
#pragma unroll
        for (int r = 0; r < 4; r++) {
            float yv = acc[nt][r] + bias;
            yv = yv > 0.f ? yv : 0.f;
            zb[wave * 16 + quad * 4 + r][col] = f2bf(yv);
        }
    }

    // ---- GEMM2
#pragma unroll
    for (int kk = 0; kk < 4; kk++)
        afr[kk] = *(const bf16x8*)&zb[wave * 16 + m16][kk * 32 + quad * 8];
#pragma unroll
    for (int nt = 0; nt < 8; nt++) acc[nt] = (f32x4){0.f, 0.f, 0.f, 0.f};
#pragma unroll
    for (int kk = 0; kk < 4; kk++) {
#pragma unroll
        for (int nt = 0; nt < 8; nt++) {
            bf16x8 bfr = *(const bf16x8*)(Wt2 + ((nt * 16 + m16) << 7) + kk * 32 + quad * 8);
            acc[nt] = __builtin_amdgcn_mfma_f32_16x16x32_bf16(afr[kk], bfr, acc[nt], 0, 0, 0);
        }
    }
#pragma unroll
    for (int nt = 0; nt < 8; nt++) {      // stage output in zb, then coalesced store
        int col = nt * 16 + m16;
        float bias = b2[col];
#pragma unroll
        for (int r = 0; r < 4; r++) {
            float ov = acc[nt][r] + bias;
            ov = ov > 0.f ? ov : 0.f;
            zb[wave * 16 + quad * 4 + r][col] = f2bf(ov);
        }
    }
#pragma unroll
    for (int p = 0; p < 4; p++) {
        int idx = p * 64 + lane;
        int r = idx >> 4, ch = idx & 15;
        if (row0 + r < NN)
            nt_store16(Hout + (size_t)(row0 + r) * DD + ch * 8, *(const uint4*)&zb[wave * 16 + r][ch * 8]);
    }
}

// ---------- mean-pool partial sums ----------
__global__ void pool_kernel(const u16* __restrict__ H2, const int* __restrict__ gstart,
                            float* __restrict__ pool) {
    int g = blockIdx.x >> 5, q = blockIdx.x & 31;
    int f = threadIdx.x;   // 0..127
    int s = gstart[g], e = gstart[g + 1];
    float sum = 0.f;
    for (int n = s + q; n < e; n += 32) sum += bf2f(H2[(size_t)n * DD + f]);
    atomicAdd(&pool[g * DD + f], sum);
}

// ---------- classifier (fp32) ----------
__global__ void cls_kernel(const float* __restrict__ pool, const int* __restrict__ gstart,
                           const float* __restrict__ Wc1, const float* __restrict__ bc1,
                           const float* __restrict__ Wc2, const float* __restrict__ bc2,
                           float* __restrict__ out) {
    __shared__ float hg[128];
    __shared__ float y1[128];
    int g = blockIdx.x;
    int t = threadIdx.x;   // 128 threads
    int cnt = gstart[g + 1] - gstart[g];
    float inv = 1.f / (float)(cnt > 1 ? cnt : 1);
    hg[t] = pool[g * DD + t] * inv;
    __syncthreads();
    float a = bc1[t];
    for (int k = 0; k < DD; k++) a += hg[k] * Wc1[k * DD + t];
    y1[t] = a > 0.f ? a : 0.f;
    __syncthreads();
    if (t < CC) {
        float o = bc2[t];
        for (int k = 0; k < DD; k++) o += y1[k] * Wc2[k * CC + t];
        out[g * CC + t] = o;
    }
}

extern "C" void kernel_launch(void* const* d_in, const int* in_sizes, int n_in,
                              void* d_out, int out_size, void* d_ws, size_t ws_size,
                              hipStream_t stream) {
    const float* h    = (const float*)d_in[0];
    const int*   src  = (const int*)d_in[1];
    const int*   dst  = (const int*)d_in[2];
    const int*   gids = (const int*)d_in[3];
    const float* W1a  = (const float*)d_in[4];
    const float* b1a  = (const float*)d_in[5];
    const float* W2a  = (const float*)d_in[6];
    const float* b2a  = (const float*)d_in[7];
    const float* W1b  = (const float*)d_in[8];
    const float* b1b  = (const float*)d_in[9];
    const float* W2b  = (const float*)d_in[10];
    const float* b2b  = (const float*)d_in[11];
    const float* Wc1  = (const float*)d_in[12];
    const float* bc1  = (const float*)d_in[13];
    const float* Wc2  = (const float*)d_in[14];
    const float* bc2  = (const float*)d_in[15];
    float* out = (float*)d_out;

    char* ws = (char*)d_ws;
    u16*   H0     = (u16*)(ws);                    // 12,800,000 B
    u16*   H1     = (u16*)(ws + 12800000);         // 12,800,000 B
    u16*   H2     = (u16*)(ws + 25600000);         // 12,800,000 B
    u16*   Wt     = (u16*)(ws + 38400000);         // 131,072 B
    float* pool   = (float*)(ws + 38531072);       // 8,192 B (zeroed by prep)
    int*   offs   = (int*)(ws + 38539264);         // 200,004 B
    int*   ssrc   = (int*)(ws + 38739268);         // 3,200,000 B
    int*   gstart = (int*)(ws + 41939268);         // 68 B
    int*   counts = (int*)(ws + 41939336);         // 153,664 B (196x196, transposed)
    int*   bsum   = (int*)(ws + 42093000);         // 604 B (scan block sums)
    int*   epack  = (int*)(ws + 42093792);         // 3,200,000 B (packed src|dstlocal)
    u16*   Z1     = H2;                            // scratch z, layer 1 (H2 written later by mlp2)
    u16*   Z2     = H0;                            // scratch z, layer 2 (H0 dead after agg1)

    prepsort_kernel<<<dim3(NBK + PBLK), dim3(256), 0, stream>>>(
        h, W1a, W2a, W1b, W2b, (int*)pool, H0, Wt, dst, counts);
    scanA_kernel<<<dim3(NSCN), dim3(256), 0, stream>>>(counts, bsum);
    scanB_kernel<<<dim3(1), dim3(256), 0, stream>>>(bsum, gids, gstart);
    scanC_kernel<<<dim3(NSCN), dim3(256), 0, stream>>>(counts, bsum);
    sortP3_kernel<<<dim3(NBK), dim3(256), 0, stream>>>(src, dst, counts, epack);
    sortP4_kernel<<<dim3(NBK), dim3(256), 0, stream>>>(epack, counts, offs, ssrc);
    agg_kernel<<<dim3((2 * NN + 31) / 32), dim3(256), 0, stream>>>(H0, offs, ssrc, Z1);
    mlp_kernel<<<dim3((NN + 63) / 64), dim3(256), 0, stream>>>(Z1, Wt, b1a, Wt + 16384, b2a, H1);
    agg_kernel<<<dim3((2 * NN + 31) / 32), dim3(256), 0, stream>>>(H1, offs, ssrc, Z2);
    mlp_kernel<<<dim3((NN + 63) / 64), dim3(256), 0, stream>>>(Z2, Wt + 32768, b1b, Wt + 49152, b2b, H2);
    pool_kernel<<<dim3(GG * 32), dim3(128), 0, stream>>>(H2, gstart, pool);
    cls_kernel<<<dim3(GG), dim3(128), 0, stream>>>(pool, gstart, Wc1, bc1, Wc2, bc2, out);
}

// Round 10
// 280.245 us; speedup vs baseline: 1.3448x; 1.0807x over previous
//
#include <hip/hip_runtime.h>
#include <stdint.h>

#define NN 50000
#define EE 800000
#define DD 128
#define GG 16
#define CC 10
#define NBK 196                   // coarse buckets of 256 nodes: 196*256 = 50176 >= NN
#define BCH 4096                  // edges per sort block: 196*4096 = 802816 >= EE
#define SMAX 5120                 // max edges per bucket (mean 4096, wide margin)
#define FT (NBK * NBK)            // 38416 flat count entries
#define NSCN ((FT + 255) / 256)   // 151 scan blocks

typedef unsigned short u16;
typedef __bf16 bf16x8 __attribute__((ext_vector_type(8)));
typedef float f32x4 __attribute__((ext_vector_type(4)));
typedef unsigned int u32x4 __attribute__((ext_vector_type(4)));
typedef float fl4 __attribute__((ext_vector_type(4)));

__device__ inline u16 f2bf(float f) {
    unsigned u = __float_as_uint(f);
    u = u + 0x7fffu + ((u >> 16) & 1u);   // RNE
    return (u16)(u >> 16);
}
__device__ inline unsigned pack2(float a, float b) {
    return (unsigned)f2bf(a) | ((unsigned)f2bf(b) << 16);
}
__device__ inline float bf2f(unsigned bits16) { return __uint_as_float(bits16 << 16); }
__device__ inline void acc8(float* a, uint4 v) {
    a[0] += __uint_as_float(v.x << 16); a[1] += __uint_as_float(v.x & 0xffff0000u);
    a[2] += __uint_as_float(v.y << 16); a[3] += __uint_as_float(v.y & 0xffff0000u);
    a[4] += __uint_as_float(v.z << 16); a[5] += __uint_as_float(v.z & 0xffff0000u);
    a[6] += __uint_as_float(v.w << 16); a[7] += __uint_as_float(v.w & 0xffff0000u);
}
__device__ inline void mand(uint4& v, int p) {     // zero the lane's contribution if !p
    unsigned m = p ? 0xffffffffu : 0u;
    v.x &= m; v.y &= m; v.z &= m; v.w &= m;
}
__device__ inline void nt_store16(void* p, uint4 v) {
    u32x4 x; x.x = v.x; x.y = v.y; x.z = v.z; x.w = v.w;
    __builtin_nontemporal_store(x, (u32x4*)p);
}
__device__ inline uint4 nt_load16(const void* p) {
    u32x4 x = __builtin_nontemporal_load((const u32x4*)p);
    uint4 r; r.x = x.x; r.y = x.y; r.z = x.z; r.w = x.w;
    return r;
}
__device__ inline float4 nt_loadf4(const float* p) {
    fl4 x = __builtin_nontemporal_load((const fl4*)p);
    float4 r; r.x = x.x; r.y = x.y; r.z = x.z; r.w = x.w;
    return r;
}

// ---------- fused prep + sortP1 ----------
#define PZ (GG * DD)                   // 2048 floats (pool) to zero
#define PC (NN * DD / 4)               // 1600000 float4 groups
#define PW (4 * DD * DD)               // 65536 weight elements
#define PTOT (PZ + PC + PW)
#define PBLK ((PTOT + 255) / 256)      // prep blocks

__global__ __launch_bounds__(256) void prepsort_kernel(
    const float* __restrict__ h,
    const float* __restrict__ a, const float* __restrict__ b,
    const float* __restrict__ c, const float* __restrict__ d,
    int* __restrict__ zbase, u16* __restrict__ H0, u16* __restrict__ wt,
    const int* __restrict__ dst, int* __restrict__ counts) {
    __shared__ int hist[NBK];
    int blk = blockIdx.x, t = threadIdx.x;
    if (blk < NBK) {                                 // ---- sortP1 part
        for (int i = t; i < NBK; i += 256) hist[i] = 0;
        __syncthreads();
        int e0 = blk * BCH, e1 = min(e0 + BCH, EE);
        for (int e = e0 + t; e < e1; e += 256) atomicAdd(&hist[dst[e] >> 8], 1);
        __syncthreads();
        for (int i = t; i < NBK; i += 256) counts[i * NBK + blk] = hist[i];  // transposed
        return;
    }
    // ---- prep part
    int i = (blk - NBK) * 256 + t;
    if (i < PZ) { zbase[i] = 0; return; }
    i -= PZ;
    if (i < PC) {
        int j = i * 4;
        float4 v = nt_loadf4(h + j);                 // h read once: don't pollute L2
        ushort4 o;
        o.x = f2bf(v.x); o.y = f2bf(v.y); o.z = f2bf(v.z); o.w = f2bf(v.w);
        *(ushort4*)(H0 + j) = o;
        return;
    }
    i -= PC;
    if (i < PW) {
        int m = i >> 14, r = i & 16383, k = r >> 7, j = r & 127;
        const float* W = (m == 0) ? a : (m == 1) ? b : (m == 2) ? c : d;
        wt[(m << 14) + (j << 7) + k] = f2bf(W[(k << 7) + j]);
    }
}

// ---------- parallel flat exclusive scan of counts_T[FT] (3-phase) ----------
__global__ __launch_bounds__(256) void scanA_kernel(int* __restrict__ counts,
                                                    int* __restrict__ bsum) {
    __shared__ int tmp[256];
    int t = threadIdx.x, idx = blockIdx.x * 256 + t;
    int v = (idx < FT) ? counts[idx] : 0;
    tmp[t] = v; __syncthreads();
    for (int off = 1; off < 256; off <<= 1) {
        int x = (t >= off) ? tmp[t - off] : 0;
        __syncthreads();
        tmp[t] += x;
        __syncthreads();
    }
    if (idx < FT) counts[idx] = tmp[t] - v;          // exclusive within block
    if (t == 255) bsum[blockIdx.x] = tmp[255];
}

__global__ __launch_bounds__(256) void scanB_kernel(int* __restrict__ bsum,
                                                    const int* __restrict__ gids,
                                                    int* __restrict__ gstart) {
    __shared__ int tmp[256];
    int t = threadIdx.x;
    if (t <= GG) {                                  // graph boundary binary search
        int lo = 0, hi = NN;
        while (lo < hi) { int mid = (lo + hi) >> 1; if (gids[mid] < t) lo = mid + 1; else hi = mid; }
        gstart[t] = lo;
    }
    int v = (t < NSCN) ? bsum[t] : 0;
    tmp[t] = v; __syncthreads();
    for (int off = 1; off < 256; off <<= 1) {
        int x = (t >= off) ? tmp[t - off] : 0;
        __syncthreads();
        tmp[t] += x;
        __syncthreads();
    }
    if (t < NSCN) bsum[t] = tmp[t] - v;              // exclusive block offsets
}

__global__ __launch_bounds__(256) void scanC_kernel(int* __restrict__ counts,
                                                    const int* __restrict__ bsum) {
    int idx = blockIdx.x * 256 + threadIdx.x;
    if (idx < FT) counts[idx] += bsum[blockIdx.x];
}

// ---------- sortP3: block-local counting sort -> run-coalesced epack writes ----------
__global__ __launch_bounds__(256) void sortP3_kernel(const int* __restrict__ src,
                                                     const int* __restrict__ dst,
                                                     const int* __restrict__ counts,
                                                     int* __restrict__ epack) {
    __shared__ int lhist[NBK + 1];   // bucket start offsets (local), sentinel at NBK
    __shared__ int lcur[NBK];        // scatter cursors
    __shared__ int goff[NBK];        // global base - local start per bucket
    __shared__ int tmp[256];
    __shared__ int sbuf[BCH];        // locally sorted packed edges (16 KB)
    int b = blockIdx.x, t = threadIdx.x;
    int e0 = b * BCH, e1 = min(e0 + BCH, EE), n = e1 - e0;

    for (int i = t; i < NBK; i += 256) lhist[i] = 0;
    __syncthreads();
    for (int e = e0 + t; e < e1; e += 256) atomicAdd(&lhist[dst[e] >> 8], 1);
    __syncthreads();
    int v = (t < NBK) ? lhist[t] : 0;
    tmp[t] = v; __syncthreads();
    for (int off = 1; off < 256; off <<= 1) {        // inclusive scan of local hist
        int x = (t >= off) ? tmp[t - off] : 0;
        __syncthreads();
        tmp[t] += x;
        __syncthreads();
    }
    if (t < NBK) {
        int excl = tmp[t] - v;
        lcur[t] = excl;
        lhist[t] = excl;
        goff[t] = counts[t * NBK + b] - excl;        // epack dest = goff[j] + local_idx
    }
    if (t == 0) lhist[NBK] = n;
    __syncthreads();
    for (int e = e0 + t; e < e1; e += 256) {         // local scatter into sbuf
        int dd = dst[e], s = src[e];
        int p = atomicAdd(&lcur[dd >> 8], 1);
        sbuf[p] = (s << 8) | (dd & 255);             // src<2^16, local dst 8b
    }
    __syncthreads();
    for (int i = t; i < n; i += 256) {               // coalesced write-out per bucket run
        int pk = sbuf[i];
        int lo = 0, hi = NBK - 1;                    // largest j with lhist[j] <= i
        while (lo < hi) { int mid = (lo + hi + 1) >> 1; if (lhist[mid] <= i) lo = mid; else hi = mid - 1; }
        epack[goff[lo] + i] = pk;
    }
}

// ---------- sortP4 (1 block/bucket): local counting sort; offs + ssrc coalesced ----------
__global__ __launch_bounds__(256) void sortP4_kernel(const int* __restrict__ epack,
                                                     const int* __restrict__ counts,
                                                     int* __restrict__ offs,
                                                     int* __restrict__ ssrc) {
    __shared__ int hist[256];
    __shared__ int curs[256];
    __shared__ int stage[SMAX];
    int j = blockIdx.x, t = threadIdx.x;
    int n0 = j << 8;
    int b0 = counts[j * NBK];                       // bucket base = flat scan at (j,0)
    int b1 = (j < NBK - 1) ? counts[(j + 1) * NBK] : EE;
    hist[t] = 0;
    __syncthreads();
    for (int e = b0 + t; e < b1; e += 256) atomicAdd(&hist[epack[e] & 255], 1);
    __syncthreads();
    int deg = hist[t];
    for (int off = 1; off < 256; off <<= 1) {       // inclusive scan
        int x = (t >= off) ? hist[t - off] : 0;
        __syncthreads();
        hist[t] += x;
        __syncthreads();
    }
    int loff = hist[t] - deg;                       // exclusive local offset
    curs[t] = loff;
    if (n0 + t <= NN) offs[n0 + t] = b0 + loff;     // block 195/t=80 writes offs[NN]=EE
    __syncthreads();
    for (int e = b0 + t; e < b1; e += 256) {
        int pk = epack[e];
        int p = atomicAdd(&curs[pk & 255], 1);
        stage[p] = pk >> 8;                         // src
    }
    __syncthreads();
    int n = b1 - b0;
    for (int i = t; i < n; i += 256) ssrc[b0 + i] = stage[i];   // coalesced
}

// ---------- aggregation: z = h + sum_{incoming} h_src ----------
__global__ __launch_bounds__(256) void agg_kernel(
    const u16* __restrict__ Hin, const int* __restrict__ offs,
    const int* __restrict__ ssrc, u16* __restrict__ Z) {
    int gid = blockIdx.x * 32 + (threadIdx.x >> 3);   // 0..99999
    int lid = threadIdx.x & 7;
    if (gid >= 2 * NN) return;
    int node = gid >> 1;
    int foff = (gid & 1) * 64 + lid * 8;              // 16B slice
    const u16* base = Hin + foff;

    float acc[8] = {0.f, 0.f, 0.f, 0.f, 0.f, 0.f, 0.f, 0.f};
    uint4 vs = *(const uint4*)(base + (size_t)node * DD);
    int e0 = offs[node], e1 = offs[node + 1];
    acc8(acc, vs);                                    // self term (eps=0)

    int nch = (e1 - e0 + 7) >> 3;
    if (nch > 0) {
        int elast = e1 - 1;
        int i0 = ssrc[e0];
        int i1 = ssrc[min(e0 + 1, elast)];
        int i2 = ssrc[min(e0 + 2, elast)];
        int i3 = ssrc[min(e0 + 3, elast)];
        int i4 = ssrc[min(e0 + 4, elast)];
        int i5 = ssrc[min(e0 + 5, elast)];
        int i6 = ssrc[min(e0 + 6, elast)];
        int i7 = ssrc[min(e0 + 7, elast)];
        int eb = e0;
        for (int c = 0; c < nch; c++) {
            int ebn = eb + 8;
            int n0 = i0, n1 = i1, n2 = i2, n3 = i3, n4 = i4, n5 = i5, n6 = i6, n7 = i7;
            if (c + 1 < nch) {                         // prefetch next chunk indices
                n0 = ssrc[ebn];
                n1 = ssrc[min(ebn + 1, elast)];
                n2 = ssrc[min(ebn + 2, elast)];
                n3 = ssrc[min(ebn + 3, elast)];
                n4 = ssrc[min(ebn + 4, elast)];
                n5 = ssrc[min(ebn + 5, elast)];
                n6 = ssrc[min(ebn + 6, elast)];
                n7 = ssrc[min(ebn + 7, elast)];
            }
            uint4 v0 = *(const uint4*)(base + (size_t)i0 * DD);
            uint4 v1 = *(const uint4*)(base + (size_t)i1 * DD);
            uint4 v2 = *(const uint4*)(base + (size_t)i2 * DD);
            uint4 v3 = *(const uint4*)(base + (size_t)i3 * DD);
            uint4 v4 = *(const uint4*)(base + (size_t)i4 * DD);
            uint4 v5 = *(const uint4*)(base + (size_t)i5 * DD);
            uint4 v6 = *(const uint4*)(base + (size_t)i6 * DD);
            uint4 v7 = *(const uint4*)(base + (size_t)i7 * DD);
            mand(v1, eb + 1 < e1); mand(v2, eb + 2 < e1); mand(v3, eb + 3 < e1);
            mand(v4, eb + 4 < e1); mand(v5, eb + 5 < e1); mand(v6, eb + 6 < e1);
            mand(v7, eb + 7 < e1);                     // slot 0 always valid
            acc8(acc, v0); acc8(acc, v1); acc8(acc, v2); acc8(acc, v3);
            acc8(acc, v4); acc8(acc, v5); acc8(acc, v6); acc8(acc, v7);
            i0 = n0; i1 = n1; i2 = n2; i3 = n3; i4 = n4; i5 = n5; i6 = n6; i7 = n7;
            eb = ebn;
        }
    }
    uint4 o;
    o.x = pack2(acc[0], acc[1]); o.y = pack2(acc[2], acc[3]);
    o.z = pack2(acc[4], acc[5]); o.w = pack2(acc[6], acc[7]);
    nt_store16(Z + (size_t)node * DD + foff, o);      // stream-once: keep L2 for gathers
}

// ---------- MLP: out = relu(relu(z@W1+b1)@W2+b2); optional fused mean-pool ----------
// block 256 = 4 waves; wave owns 16 rows; wave-private until the optional pool barrier.
__global__ __launch_bounds__(256) void mlp_kernel(
    const u16* __restrict__ Zin, const u16* __restrict__ Wt1, const float* __restrict__ b1,
    const u16* __restrict__ Wt2, const float* __restrict__ b2,
    u16* __restrict__ Hout, const int* __restrict__ gids, float* __restrict__ pool) {
    __shared__ u16 zb[64][136];   // row stride 272B: 16B-aligned, wave-private 16-row tiles
    __shared__ int garr[64];
    const int tid = threadIdx.x;
    const int wave = tid >> 6;
    const int lane = tid & 63;
    const int m16 = lane & 15;
    const int quad = lane >> 4;
    const int row0 = blockIdx.x * 64 + wave * 16;
    const int brow0 = blockIdx.x * 64;

    if (pool && tid < 64) garr[tid] = (brow0 + tid < NN) ? gids[brow0 + tid] : 0;

    // stage 16 rows x 256B, fully coalesced; z is read-once
#pragma unroll
    for (int p = 0; p < 4; p++) {
        int idx = p * 64 + lane;          // 0..255 16B-chunks
        int r = idx >> 4, ch = idx & 15;
        if (row0 + r < NN) {
            uint4 v = nt_load16(Zin + (size_t)(row0 + r) * DD + ch * 8);
            *(uint4*)&zb[wave * 16 + r][ch * 8] = v;
        }
    }

    // ---- GEMM1
    bf16x8 afr[4];
#pragma unroll
    for (int kk = 0; kk < 4; kk++)
        afr[kk] = *(const bf16x8*)&zb[wave * 16 + m16][kk * 32 + quad * 8];
    f32x4 acc[8];
#pragma unroll
    for (int nt = 0; nt < 8; nt++) acc[nt] = (f32x4){0.f, 0.f, 0.f, 0.f};
#pragma unroll
    for (int kk = 0; kk < 4; kk++) {
#pragma unroll
        for (int nt = 0; nt < 8; nt++) {
            bf16x8 bfr = *(const bf16x8*)(Wt1 + ((nt * 16 + m16) << 7) + kk * 32 + quad * 8);
            acc[nt] = __builtin_amdgcn_mfma_f32_16x16x32_bf16(afr[kk], bfr, acc[nt], 0, 0, 0);
        }
    }
#pragma unroll
    for (int nt = 0; nt < 8; nt++) {      // y -> zb (zb dead after afr read; wave-private)
        int col = nt * 16 + m16;
        float bias = b1[col];
#pragma unroll
        for (int r = 0; r < 4; r++) {
            float yv = acc[nt][r] + bias;
            yv = yv > 0.f ? yv : 0.f;
            zb[wave * 16 + quad * 4 + r][col] = f2bf(yv);
        }
    }

    // ---- GEMM2
#pragma unroll
    for (int kk = 0; kk < 4; kk++)
        afr[kk] = *(const bf16x8*)&zb[wave * 16 + m16][kk * 32 + quad * 8];
#pragma unroll
    for (int nt = 0; nt < 8; nt++) acc[nt] = (f32x4){0.f, 0.f, 0.f, 0.f};
#pragma unroll
    for (int kk = 0; kk < 4; kk++) {
#pragma unroll
        for (int nt = 0; nt < 8; nt++) {
            bf16x8 bfr = *(const bf16x8*)(Wt2 + ((nt * 16 + m16) << 7) + kk * 32 + quad * 8);
            acc[nt] = __builtin_amdgcn_mfma_f32_16x16x32_bf16(afr[kk], bfr, acc[nt], 0, 0, 0);
        }
    }
#pragma unroll
    for (int nt = 0; nt < 8; nt++) {      // stage output in zb, then coalesced store
        int col = nt * 16 + m16;
        float bias = b2[col];
#pragma unroll
        for (int r = 0; r < 4; r++) {
            float ov = acc[nt][r] + bias;
            ov = ov > 0.f ? ov : 0.f;
            zb[wave * 16 + quad * 4 + r][col] = f2bf(ov);
        }
    }
#pragma unroll
    for (int p = 0; p < 4; p++) {
        int idx = p * 64 + lane;
        int r = idx >> 4, ch = idx & 15;
        if (row0 + r < NN)
            nt_store16(Hout + (size_t)(row0 + r) * DD + ch * 8, *(const uint4*)&zb[wave * 16 + r][ch * 8]);
    }

    // ---- fused mean-pool partial sums (H2 tile already staged in zb)
    if (pool) {
        __syncthreads();
        if (tid < DD) {
            int cur = garr[0];
            float s = 0.f;
            for (int r = 0; r < 64; r++) {
                if (brow0 + r >= NN) break;
                int g = garr[r];
                if (g != cur) { atomicAdd(&pool[cur * DD + tid], s); s = 0.f; cur = g; }
                s += bf2f((unsigned)zb[r][tid]);
            }
            atomicAdd(&pool[cur * DD + tid], s);
        }
    }
}

// ---------- classifier (fp32) ----------
__global__ void cls_kernel(const float* __restrict__ pool, const int* __restrict__ gstart,
                           const float* __restrict__ Wc1, const float* __restrict__ bc1,
                           const float* __restrict__ Wc2, const float* __restrict__ bc2,
                           float* __restrict__ out) {
    __shared__ float hg[128];
    __shared__ float y1[128];
    int g = blockIdx.x;
    int t = threadIdx.x;   // 128 threads
    int cnt = gstart[g + 1] - gstart[g];
    float inv = 1.f / (float)(cnt > 1 ? cnt : 1);
    hg[t] = pool[g * DD + t] * inv;
    __syncthreads();
    float a = bc1[t];
    for (int k = 0; k < DD; k++) a += hg[k] * Wc1[k * DD + t];
    y1[t] = a > 0.f ? a : 0.f;
    __syncthreads();
    if (t < CC) {
        float o = bc2[t];
        for (int k = 0; k < DD; k++) o += y1[k] * Wc2[k * CC + t];
        out[g * CC + t] = o;
    }
}

extern "C" void kernel_launch(void* const* d_in, const int* in_sizes, int n_in,
                              void* d_out, int out_size, void* d_ws, size_t ws_size,
                              hipStream_t stream) {
    const float* h    = (const float*)d_in[0];
    const int*   src  = (const int*)d_in[1];
    const int*   dst  = (const int*)d_in[2];
    const int*   gids = (const int*)d_in[3];
    const float* W1a  = (const float*)d_in[4];
    const float* b1a  = (const float*)d_in[5];
    const float* W2a  = (const float*)d_in[6];
    const float* b2a  = (const float*)d_in[7];
    const float* W1b  = (const float*)d_in[8];
    const float* b1b  = (const float*)d_in[9];
    const float* W2b  = (const float*)d_in[10];
    const float* b2b  = (const float*)d_in[11];
    const float* Wc1  = (const float*)d_in[12];
    const float* bc1  = (const float*)d_in[13];
    const float* Wc2  = (const float*)d_in[14];
    const float* bc2  = (const float*)d_in[15];
    float* out = (float*)d_out;

    char* ws = (char*)d_ws;
    u16*   H0     = (u16*)(ws);                    // 12,800,000 B
    u16*   H1     = (u16*)(ws + 12800000);         // 12,800,000 B
    u16*   H2     = (u16*)(ws + 25600000);         // 12,800,000 B
    u16*   Wt     = (u16*)(ws + 38400000);         // 131,072 B
    float* pool   = (float*)(ws + 38531072);       // 8,192 B (zeroed by prep)
    int*   offs   = (int*)(ws + 38539264);         // 200,004 B
    int*   ssrc   = (int*)(ws + 38739268);         // 3,200,000 B
    int*   gstart = (int*)(ws + 41939268);         // 68 B
    int*   counts = (int*)(ws + 41939336);         // 153,664 B (196x196, transposed)
    int*   bsum   = (int*)(ws + 42093000);         // 604 B (scan block sums)
    int*   epack  = (int*)(ws + 42093792);         // 3,200,000 B (packed src|dstlocal)
    u16*   Z1     = H2;                            // scratch z, layer 1 (H2 written later by mlp2)
    u16*   Z2     = H0;                            // scratch z, layer 2 (H0 dead after agg1)

    prepsort_kernel<<<dim3(NBK + PBLK), dim3(256), 0, stream>>>(
        h, W1a, W2a, W1b, W2b, (int*)pool, H0, Wt, dst, counts);
    scanA_kernel<<<dim3(NSCN), dim3(256), 0, stream>>>(counts, bsum);
    scanB_kernel<<<dim3(1), dim3(256), 0, stream>>>(bsum, gids, gstart);
    scanC_kernel<<<dim3(NSCN), dim3(256), 0, stream>>>(counts, bsum);
    sortP3_kernel<<<dim3(NBK), dim3(256), 0, stream>>>(src, dst, counts, epack);
    sortP4_kernel<<<dim3(NBK), dim3(256), 0, stream>>>(epack, counts, offs, ssrc);
    agg_kernel<<<dim3((2 * NN + 31) / 32), dim3(256), 0, stream>>>(H0, offs, ssrc, Z1);
    mlp_kernel<<<dim3((NN + 63) / 64), dim3(256), 0, stream>>>(Z1, Wt, b1a, Wt + 16384, b2a, H1, gids, nullptr);
    agg_kernel<<<dim3((2 * NN + 31) / 32), dim3(256), 0, stream>>>(H1, offs, ssrc, Z2);
    mlp_kernel<<<dim3((NN + 63) / 64), dim3(256), 0, stream>>>(Z2, Wt + 32768, b1b, Wt + 49152, b2b, H2, gids, pool);
    cls_kernel<<<dim3(GG), dim3(128), 0, stream>>>(pool, gstart, Wc1, bc1, Wc2, bc2, out);
}

// Round 11
// 252.338 us; speedup vs baseline: 1.4935x; 1.1106x over previous
//
#include <hip/hip_runtime.h>
#include <stdint.h>

#define NN 50000
#define EE 800000
#define DD 128
#define GG 16
#define CC 10
#define NBK 196                   // coarse buckets of 256 nodes: 196*256 = 50176 >= NN
#define BCH 4096                  // edges per sort block: 196*4096 = 802816 >= EE
#define SMAX 5120                 // max edges per bucket (mean 4096, wide margin)
#define FT (NBK * NBK)            // 38416 flat count entries
#define NSCN ((FT + 255) / 256)   // 151 scan blocks
#define NT 782                    // 64-row MLP tiles

typedef unsigned short u16;
typedef __bf16 bf16x8 __attribute__((ext_vector_type(8)));
typedef float f32x4 __attribute__((ext_vector_type(4)));
typedef unsigned int u32x4 __attribute__((ext_vector_type(4)));
typedef float fl4 __attribute__((ext_vector_type(4)));

__device__ inline u16 f2bf(float f) {
    unsigned u = __float_as_uint(f);
    u = u + 0x7fffu + ((u >> 16) & 1u);   // RNE
    return (u16)(u >> 16);
}
__device__ inline unsigned pack2(float a, float b) {
    return (unsigned)f2bf(a) | ((unsigned)f2bf(b) << 16);
}
__device__ inline float bf2f(unsigned bits16) { return __uint_as_float(bits16 << 16); }
__device__ inline void acc8(float* a, uint4 v) {
    a[0] += __uint_as_float(v.x << 16); a[1] += __uint_as_float(v.x & 0xffff0000u);
    a[2] += __uint_as_float(v.y << 16); a[3] += __uint_as_float(v.y & 0xffff0000u);
    a[4] += __uint_as_float(v.z << 16); a[5] += __uint_as_float(v.z & 0xffff0000u);
    a[6] += __uint_as_float(v.w << 16); a[7] += __uint_as_float(v.w & 0xffff0000u);
}
__device__ inline void mand(uint4& v, int p) {     // zero the lane's contribution if !p
    unsigned m = p ? 0xffffffffu : 0u;
    v.x &= m; v.y &= m; v.z &= m; v.w &= m;
}
__device__ inline void nt_store16(void* p, uint4 v) {
    u32x4 x; x.x = v.x; x.y = v.y; x.z = v.z; x.w = v.w;
    __builtin_nontemporal_store(x, (u32x4*)p);
}
__device__ inline float4 nt_loadf4(const float* p) {
    fl4 x = __builtin_nontemporal_load((const fl4*)p);
    float4 r; r.x = x.x; r.y = x.y; r.z = x.z; r.w = x.w;
    return r;
}

// ---------- fused prep + sortP1 ----------
#define PZ (GG * DD)                   // 2048 floats (pool) to zero
#define PC (NN * DD / 4)               // 1600000 float4 groups
#define PW (4 * DD * DD)               // 65536 weight elements
#define PTOT (PZ + PC + PW)
#define PBLK ((PTOT + 255) / 256)      // prep blocks

__global__ __launch_bounds__(256) void prepsort_kernel(
    const float* __restrict__ h,
    const float* __restrict__ a, const float* __restrict__ b,
    const float* __restrict__ c, const float* __restrict__ d,
    int* __restrict__ zbase, u16* __restrict__ H0, u16* __restrict__ wt,
    const int* __restrict__ dst, int* __restrict__ counts) {
    __shared__ int hist[NBK];
    int blk = blockIdx.x, t = threadIdx.x;
    if (blk < NBK) {                                 // ---- sortP1 part
        for (int i = t; i < NBK; i += 256) hist[i] = 0;
        __syncthreads();
        int e0 = blk * BCH, e1 = min(e0 + BCH, EE);
        for (int e = e0 + t; e < e1; e += 256) atomicAdd(&hist[dst[e] >> 8], 1);
        __syncthreads();
        for (int i = t; i < NBK; i += 256) counts[i * NBK + blk] = hist[i];  // transposed
        return;
    }
    // ---- prep part
    int i = (blk - NBK) * 256 + t;
    if (i < PZ) { zbase[i] = 0; return; }
    i -= PZ;
    if (i < PC) {
        int j = i * 4;
        float4 v = nt_loadf4(h + j);                 // h read once: don't pollute L2
        ushort4 o;
        o.x = f2bf(v.x); o.y = f2bf(v.y); o.z = f2bf(v.z); o.w = f2bf(v.w);
        *(ushort4*)(H0 + j) = o;
        return;
    }
    i -= PC;
    if (i < PW) {
        int m = i >> 14, r = i & 16383, k = r >> 7, j = r & 127;
        const float* W = (m == 0) ? a : (m == 1) ? b : (m == 2) ? c : d;
        wt[(m << 14) + (j << 7) + k] = f2bf(W[(k << 7) + j]);
    }
}

// ---------- parallel flat exclusive scan of counts_T[FT] (3-phase) ----------
__global__ __launch_bounds__(256) void scanA_kernel(int* __restrict__ counts,
                                                    int* __restrict__ bsum) {
    __shared__ int tmp[256];
    int t = threadIdx.x, idx = blockIdx.x * 256 + t;
    int v = (idx < FT) ? counts[idx] : 0;
    tmp[t] = v; __syncthreads();
    for (int off = 1; off < 256; off <<= 1) {
        int x = (t >= off) ? tmp[t - off] : 0;
        __syncthreads();
        tmp[t] += x;
        __syncthreads();
    }
    if (idx < FT) counts[idx] = tmp[t] - v;          // exclusive within block
    if (t == 255) bsum[blockIdx.x] = tmp[255];
}

__global__ __launch_bounds__(256) void scanB_kernel(int* __restrict__ bsum,
                                                    const int* __restrict__ gids,
                                                    int* __restrict__ gstart) {
    __shared__ int tmp[256];
    int t = threadIdx.x;
    if (t <= GG) {                                  // graph boundary binary search
        int lo = 0, hi = NN;
        while (lo < hi) { int mid = (lo + hi) >> 1; if (gids[mid] < t) lo = mid + 1; else hi = mid; }
        gstart[t] = lo;
    }
    int v = (t < NSCN) ? bsum[t] : 0;
    tmp[t] = v; __syncthreads();
    for (int off = 1; off < 256; off <<= 1) {
        int x = (t >= off) ? tmp[t - off] : 0;
        __syncthreads();
        tmp[t] += x;
        __syncthreads();
    }
    if (t < NSCN) bsum[t] = tmp[t] - v;              // exclusive block offsets
}

__global__ __launch_bounds__(256) void scanC_kernel(int* __restrict__ counts,
                                                    const int* __restrict__ bsum) {
    int idx = blockIdx.x * 256 + threadIdx.x;
    if (idx < FT) counts[idx] += bsum[blockIdx.x];
}

// ---------- sortP3: block-local counting sort -> run-coalesced epack writes ----------
__global__ __launch_bounds__(256) void sortP3_kernel(const int* __restrict__ src,
                                                     const int* __restrict__ dst,
                                                     const int* __restrict__ counts,
                                                     int* __restrict__ epack) {
    __shared__ int lhist[NBK + 1];
    __shared__ int lcur[NBK];
    __shared__ int goff[NBK];
    __shared__ int tmp[256];
    __shared__ int sbuf[BCH];        // locally sorted packed edges (16 KB)
    int b = blockIdx.x, t = threadIdx.x;
    int e0 = b * BCH, e1 = min(e0 + BCH, EE), n = e1 - e0;

    for (int i = t; i < NBK; i += 256) lhist[i] = 0;
    __syncthreads();
    for (int e = e0 + t; e < e1; e += 256) atomicAdd(&lhist[dst[e] >> 8], 1);
    __syncthreads();
    int v = (t < NBK) ? lhist[t] : 0;
    tmp[t] = v; __syncthreads();
    for (int off = 1; off < 256; off <<= 1) {        // inclusive scan of local hist
        int x = (t >= off) ? tmp[t - off] : 0;
        __syncthreads();
        tmp[t] += x;
        __syncthreads();
    }
    if (t < NBK) {
        int excl = tmp[t] - v;
        lcur[t] = excl;
        lhist[t] = excl;
        goff[t] = counts[t * NBK + b] - excl;        // epack dest = goff[j] + local_idx
    }
    if (t == 0) lhist[NBK] = n;
    __syncthreads();
    for (int e = e0 + t; e < e1; e += 256) {         // local scatter into sbuf
        int dd = dst[e], s = src[e];
        int p = atomicAdd(&lcur[dd >> 8], 1);
        sbuf[p] = (s << 8) | (dd & 255);             // src<2^16, local dst 8b
    }
    __syncthreads();
    for (int i = t; i < n; i += 256) {               // coalesced write-out per bucket run
        int pk = sbuf[i];
        int lo = 0, hi = NBK - 1;                    // largest j with lhist[j] <= i
        while (lo < hi) { int mid = (lo + hi + 1) >> 1; if (lhist[mid] <= i) lo = mid; else hi = mid - 1; }
        epack[goff[lo] + i] = pk;
    }
}

// ---------- sortP4 (1 block/bucket): local counting sort; offs + ssrc coalesced ----------
__global__ __launch_bounds__(256) void sortP4_kernel(const int* __restrict__ epack,
                                                     const int* __restrict__ counts,
                                                     int* __restrict__ offs,
                                                     int* __restrict__ ssrc) {
    __shared__ int hist[256];
    __shared__ int curs[256];
    __shared__ int stage[SMAX];
    int j = blockIdx.x, t = threadIdx.x;
    int n0 = j << 8;
    int b0 = counts[j * NBK];                       // bucket base = flat scan at (j,0)
    int b1 = (j < NBK - 1) ? counts[(j + 1) * NBK] : EE;
    hist[t] = 0;
    __syncthreads();
    for (int e = b0 + t; e < b1; e += 256) atomicAdd(&hist[epack[e] & 255], 1);
    __syncthreads();
    int deg = hist[t];
    for (int off = 1; off < 256; off <<= 1) {       // inclusive scan
        int x = (t >= off) ? hist[t - off] : 0;
        __syncthreads();
        hist[t] += x;
        __syncthreads();
    }
    int loff = hist[t] - deg;                       // exclusive local offset
    curs[t] = loff;
    if (n0 + t <= NN) offs[n0 + t] = b0 + loff;     // block 195/t=80 writes offs[NN]=EE
    __syncthreads();
    for (int e = b0 + t; e < b1; e += 256) {
        int pk = epack[e];
        int p = atomicAdd(&curs[pk & 255], 1);
        stage[p] = pk >> 8;                         // src
    }
    __syncthreads();
    int n = b1 - b0;
    for (int i = t; i < n; i += 256) ssrc[b0 + i] = stage[i];   // coalesced
}

// ---------- aggregation: z = h + sum_{incoming} h_src ----------
__global__ __launch_bounds__(256) void agg_kernel(
    const u16* __restrict__ Hin, const int* __restrict__ offs,
    const int* __restrict__ ssrc, u16* __restrict__ Z) {
    int gid = blockIdx.x * 32 + (threadIdx.x >> 3);   // 0..99999
    int lid = threadIdx.x & 7;
    if (gid >= 2 * NN) return;
    int node = gid >> 1;
    int foff = (gid & 1) * 64 + lid * 8;              // 16B slice
    const u16* base = Hin + foff;

    float acc[8] = {0.f, 0.f, 0.f, 0.f, 0.f, 0.f, 0.f, 0.f};
    uint4 vs = *(const uint4*)(base + (size_t)node * DD);
    int e0 = offs[node], e1 = offs[node + 1];
    acc8(acc, vs);                                    // self term (eps=0)

    int nch = (e1 - e0 + 7) >> 3;
    if (nch > 0) {
        int elast = e1 - 1;
        int i0 = ssrc[e0];
        int i1 = ssrc[min(e0 + 1, elast)];
        int i2 = ssrc[min(e0 + 2, elast)];
        int i3 = ssrc[min(e0 + 3, elast)];
        int i4 = ssrc[min(e0 + 4, elast)];
        int i5 = ssrc[min(e0 + 5, elast)];
        int i6 = ssrc[min(e0 + 6, elast)];
        int i7 = ssrc[min(e0 + 7, elast)];
        int eb = e0;
        for (int c = 0; c < nch; c++) {
            int ebn = eb + 8;
            int n0 = i0, n1 = i1, n2 = i2, n3 = i3, n4 = i4, n5 = i5, n6 = i6, n7 = i7;
            if (c + 1 < nch) {                         // prefetch next chunk indices
                n0 = ssrc[ebn];
                n1 = ssrc[min(ebn + 1, elast)];
                n2 = ssrc[min(ebn + 2, elast)];
                n3 = ssrc[min(ebn + 3, elast)];
                n4 = ssrc[min(ebn + 4, elast)];
                n5 = ssrc[min(ebn + 5, elast)];
                n6 = ssrc[min(ebn + 6, elast)];
                n7 = ssrc[min(ebn + 7, elast)];
            }
            uint4 v0 = *(const uint4*)(base + (size_t)i0 * DD);
            uint4 v1 = *(const uint4*)(base + (size_t)i1 * DD);
            uint4 v2 = *(const uint4*)(base + (size_t)i2 * DD);
            uint4 v3 = *(const uint4*)(base + (size_t)i3 * DD);
            uint4 v4 = *(const uint4*)(base + (size_t)i4 * DD);
            uint4 v5 = *(const uint4*)(base + (size_t)i5 * DD);
            uint4 v6 = *(const uint4*)(base + (size_t)i6 * DD);
            uint4 v7 = *(const uint4*)(base + (size_t)i7 * DD);
            mand(v1, eb + 1 < e1); mand(v2, eb + 2 < e1); mand(v3, eb + 3 < e1);
            mand(v4, eb + 4 < e1); mand(v5, eb + 5 < e1); mand(v6, eb + 6 < e1);
            mand(v7, eb + 7 < e1);                     // slot 0 always valid
            acc8(acc, v0); acc8(acc, v1); acc8(acc, v2); acc8(acc, v3);
            acc8(acc, v4); acc8(acc, v5); acc8(acc, v6); acc8(acc, v7);
            i0 = n0; i1 = n1; i2 = n2; i3 = n3; i4 = n4; i5 = n5; i6 = n6; i7 = n7;
            eb = ebn;
        }
    }
    uint4 o;
    o.x = pack2(acc[0], acc[1]); o.y = pack2(acc[2], acc[3]);
    o.z = pack2(acc[4], acc[5]); o.w = pack2(acc[6], acc[7]);
    nt_store16(Z + (size_t)node * DD + foff, o);      // stream-once: keep L2 for gathers
}

// ---------- MLP v2: persistent blocks, W1 in LDS (fragment-ordered), W2 in regs ----------
// 256 blocks x 256 threads grid-stride over 782 tiles. All-register z path with
// one-tile-ahead prefetch; yb LDS only for the y/out transposes (wave-private).
__global__ __launch_bounds__(256, 1) void mlp_kernel(
    const u16* __restrict__ Zin, const u16* __restrict__ Wt1, const float* __restrict__ b1,
    const u16* __restrict__ Wt2, const float* __restrict__ b2,
    u16* __restrict__ Hout, const int* __restrict__ gids, float* __restrict__ pool) {
    __shared__ __align__(16) u16 w1f[16384];   // 32KB fragment-ordered W1
    __shared__ __align__(16) u16 yb[64][136];  // 17.4KB transpose staging
    const int tid = threadIdx.x;
    const int wave = tid >> 6;
    const int lane = tid & 63;
    const int m16 = lane & 15;
    const int quad = lane >> 4;

    // stage W1 fragment-ordered: chunk c -> (kk=c>>9, nt=(c>>6)&7, lane=c&63)
    for (int cidx = tid; cidx < 2048; cidx += 256) {
        int ln = cidx & 63, nt = (cidx >> 6) & 7, kk = cidx >> 9;
        int gofs = ((nt * 16 + (ln & 15)) << 7) + kk * 32 + (ln >> 4) * 8;
        *(uint4*)&w1f[cidx * 8] = *(const uint4*)(Wt1 + gofs);
    }
    // W2 fragments -> registers (loaded once, reused for all tiles)
    bf16x8 w2r[4][8];
#pragma unroll
    for (int kk = 0; kk < 4; kk++)
#pragma unroll
        for (int nt = 0; nt < 8; nt++)
            w2r[kk][nt] = *(const bf16x8*)(Wt2 + ((nt * 16 + m16) << 7) + kk * 32 + quad * 8);
    // biases hoisted
    float bias1[8], bias2[8];
#pragma unroll
    for (int nt = 0; nt < 8; nt++) {
        bias1[nt] = b1[nt * 16 + m16];
        bias2[nt] = b2[nt * 16 + m16];
    }
    __syncthreads();

    int tile = blockIdx.x;
    bf16x8 afr[4], afrN[4];
    {
        size_t row = (size_t)(tile * 64 + wave * 16 + m16);
#pragma unroll
        for (int kk = 0; kk < 4; kk++)
            afr[kk] = *(const bf16x8*)(Zin + row * DD + kk * 32 + quad * 8);
    }
    for (; tile < NT; tile += 256) {
        int nxt = tile + 256;
        if (nxt < NT) {                              // prefetch next tile's A-fragments
            size_t row = (size_t)(nxt * 64 + wave * 16 + m16);
#pragma unroll
            for (int kk = 0; kk < 4; kk++)
                afrN[kk] = *(const bf16x8*)(Zin + row * DD + kk * 32 + quad * 8);
        }
        const int row0 = tile * 64 + wave * 16;

        // ---- GEMM1 (B from LDS, conflict-free fragment order)
        f32x4 acc[8];
#pragma unroll
        for (int nt = 0; nt < 8; nt++) acc[nt] = (f32x4){0.f, 0.f, 0.f, 0.f};
#pragma unroll
        for (int kk = 0; kk < 4; kk++) {
#pragma unroll
            for (int nt = 0; nt < 8; nt++) {
                bf16x8 bfr = *(const bf16x8*)&w1f[(((kk * 8 + nt) * 64) + lane) * 8];
                acc[nt] = __builtin_amdgcn_mfma_f32_16x16x32_bf16(afr[kk], bfr, acc[nt], 0, 0, 0);
            }
        }
#pragma unroll
        for (int nt = 0; nt < 8; nt++) {             // y -> yb (wave-private)
            int col = nt * 16 + m16;
#pragma unroll
            for (int r = 0; r < 4; r++) {
                float yv = acc[nt][r] + bias1[nt];
                yv = yv > 0.f ? yv : 0.f;
                yb[wave * 16 + quad * 4 + r][col] = f2bf(yv);
            }
        }

        // ---- GEMM2 (B entirely in registers — zero loads)
        bf16x8 afr2[4];
#pragma unroll
        for (int kk = 0; kk < 4; kk++)
            afr2[kk] = *(const bf16x8*)&yb[wave * 16 + m16][kk * 32 + quad * 8];
#pragma unroll
        for (int nt = 0; nt < 8; nt++) acc[nt] = (f32x4){0.f, 0.f, 0.f, 0.f};
#pragma unroll
        for (int kk = 0; kk < 4; kk++) {
#pragma unroll
            for (int nt = 0; nt < 8; nt++)
                acc[nt] = __builtin_amdgcn_mfma_f32_16x16x32_bf16(afr2[kk], w2r[kk][nt], acc[nt], 0, 0, 0);
        }
#pragma unroll
        for (int nt = 0; nt < 8; nt++) {             // out -> yb
            int col = nt * 16 + m16;
#pragma unroll
            for (int r = 0; r < 4; r++) {
                float ov = acc[nt][r] + bias2[nt];
                ov = ov > 0.f ? ov : 0.f;
                yb[wave * 16 + quad * 4 + r][col] = f2bf(ov);
            }
        }
        if (!pool) {                                 // layer 1: store H (cached; agg2 gathers it)
#pragma unroll
            for (int p = 0; p < 4; p++) {
                int idx = p * 64 + lane;
                int r = idx >> 4, ch = idx & 15;
                if (row0 - wave * 16 + ((wave * 16) + r) < NN) {}   // keep r mapping clear
                int grow = row0 + r;
                if (grow < NN)
                    *(uint4*)(Hout + (size_t)grow * DD + ch * 8) = *(const uint4*)&yb[wave * 16 + r][ch * 8];
            }
        } else {                                     // layer 2: fused mean-pool, no H store
            int prow = row0 + m16;
            int g = gids[min(prow, NN - 1)];
#pragma unroll
            for (int fsel = 0; fsel < 2; fsel++) {
                int f = lane + fsel * 64;
                float s = 0.f;
                int cur = __shfl(g, 0);
                for (int r = 0; r < 16; r++) {
                    int gr = __shfl(g, r);
                    float v = (row0 + r < NN) ? bf2f((unsigned)yb[wave * 16 + r][f]) : 0.f;
                    if (gr != cur) { atomicAdd(&pool[cur * DD + f], s); s = 0.f; cur = gr; }
                    s += v;
                }
                atomicAdd(&pool[cur * DD + f], s);
            }
        }
#pragma unroll
        for (int kk = 0; kk < 4; kk++) afr[kk] = afrN[kk];   // rotate prefetch
    }
}

// ---------- classifier (fp32) ----------
__global__ void cls_kernel(const float* __restrict__ pool, const int* __restrict__ gstart,
                           const float* __restrict__ Wc1, const float* __restrict__ bc1,
                           const float* __restrict__ Wc2, const float* __restrict__ bc2,
                           float* __restrict__ out) {
    __shared__ float hg[128];
    __shared__ float y1[128];
    int g = blockIdx.x;
    int t = threadIdx.x;   // 128 threads
    int cnt = gstart[g + 1] - gstart[g];
    float inv = 1.f / (float)(cnt > 1 ? cnt : 1);
    hg[t] = pool[g * DD + t] * inv;
    __syncthreads();
    float a = bc1[t];
    for (int k = 0; k < DD; k++) a += hg[k] * Wc1[k * DD + t];
    y1[t] = a > 0.f ? a : 0.f;
    __syncthreads();
    if (t < CC) {
        float o = bc2[t];
        for (int k = 0; k < DD; k++) o += y1[k] * Wc2[k * CC + t];
        out[g * CC + t] = o;
    }
}

extern "C" void kernel_launch(void* const* d_in, const int* in_sizes, int n_in,
                              void* d_out, int out_size, void* d_ws, size_t ws_size,
                              hipStream_t stream) {
    const float* h    = (const float*)d_in[0];
    const int*   src  = (const int*)d_in[1];
    const int*   dst  = (const int*)d_in[2];
    const int*   gids = (const int*)d_in[3];
    const float* W1a  = (const float*)d_in[4];
    const float* b1a  = (const float*)d_in[5];
    const float* W2a  = (const float*)d_in[6];
    const float* b2a  = (const float*)d_in[7];
    const float* W1b  = (const float*)d_in[8];
    const float* b1b  = (const float*)d_in[9];
    const float* W2b  = (const float*)d_in[10];
    const float* b2b  = (const float*)d_in[11];
    const float* Wc1  = (const float*)d_in[12];
    const float* bc1  = (const float*)d_in[13];
    const float* Wc2  = (const float*)d_in[14];
    const float* bc2  = (const float*)d_in[15];
    float* out = (float*)d_out;

    char* ws = (char*)d_ws;
    u16*   H0     = (u16*)(ws);                    // 12,800,000 B
    u16*   H1     = (u16*)(ws + 12800000);         // 12,800,000 B
    u16*   H2     = (u16*)(ws + 25600000);         // 12,800,000 B
    u16*   Wt     = (u16*)(ws + 38400000);         // 131,072 B
    float* pool   = (float*)(ws + 38531072);       // 8,192 B (zeroed by prep)
    int*   offs   = (int*)(ws + 38539264);         // 200,004 B
    int*   ssrc   = (int*)(ws + 38739268);         // 3,200,000 B
    int*   gstart = (int*)(ws + 41939268);         // 68 B
    int*   counts = (int*)(ws + 41939336);         // 153,664 B (196x196, transposed)
    int*   bsum   = (int*)(ws + 42093000);         // 604 B (scan block sums)
    int*   epack  = (int*)(ws + 42093792);         // 3,200,000 B (packed src|dstlocal)
    u16*   Z1     = H2;                            // scratch z, layer 1 (H2 unused otherwise)
    u16*   Z2     = H0;                            // scratch z, layer 2 (H0 dead after agg1)

    prepsort_kernel<<<dim3(NBK + PBLK), dim3(256), 0, stream>>>(
        h, W1a, W2a, W1b, W2b, (int*)pool, H0, Wt, dst, counts);
    scanA_kernel<<<dim3(NSCN), dim3(256), 0, stream>>>(counts, bsum);
    scanB_kernel<<<dim3(1), dim3(256), 0, stream>>>(bsum, gids, gstart);
    scanC_kernel<<<dim3(NSCN), dim3(256), 0, stream>>>(counts, bsum);
    sortP3_kernel<<<dim3(NBK), dim3(256), 0, stream>>>(src, dst, counts, epack);
    sortP4_kernel<<<dim3(NBK), dim3(256), 0, stream>>>(epack, counts, offs, ssrc);
    agg_kernel<<<dim3((2 * NN + 31) / 32), dim3(256), 0, stream>>>(H0, offs, ssrc, Z1);
    mlp_kernel<<<dim3(256), dim3(256), 0, stream>>>(Z1, Wt, b1a, Wt + 16384, b2a, H1, gids, nullptr);
    agg_kernel<<<dim3((2 * NN + 31) / 32), dim3(256), 0, stream>>>(H1, offs, ssrc, Z2);
    mlp_kernel<<<dim3(256), dim3(256), 0, stream>>>(Z2, Wt + 32768, b1b, Wt + 49152, b2b, H2, gids, pool);
    cls_kernel<<<dim3(GG), dim3(128), 0, stream>>>(pool, gstart, Wc1, bc1, Wc2, bc2, out);
}

// Round 12
// 250.824 us; speedup vs baseline: 1.5025x; 1.0060x over previous
//
#include <hip/hip_runtime.h>
#include <stdint.h>

#define NN 50000
#define EE 800000
#define DD 128
#define GG 16
#define CC 10
#define NBK 196                   // coarse buckets of 256 nodes: 196*256 = 50176 >= NN
#define BCH 4096                  // edges per sort block: 196*4096 = 802816 >= EE
#define SMAX 5120                 // max edges per bucket (mean 4096, wide margin)
#define FT (NBK * NBK)            // 38416 flat count entries
#define NSCN ((FT + 255) / 256)   // 151 scan blocks
#define NT 782                    // 64-row MLP tiles

typedef unsigned short u16;
typedef __bf16 bf16x8 __attribute__((ext_vector_type(8)));
typedef float f32x4 __attribute__((ext_vector_type(4)));
typedef unsigned int u32x4 __attribute__((ext_vector_type(4)));
typedef float fl4 __attribute__((ext_vector_type(4)));

__device__ inline u16 f2bf(float f) {
    unsigned u = __float_as_uint(f);
    u = u + 0x7fffu + ((u >> 16) & 1u);   // RNE
    return (u16)(u >> 16);
}
__device__ inline unsigned pack2(float a, float b) {
    return (unsigned)f2bf(a) | ((unsigned)f2bf(b) << 16);
}
__device__ inline float bf2f(unsigned bits16) { return __uint_as_float(bits16 << 16); }
__device__ inline void acc8(float* a, uint4 v) {
    a[0] += __uint_as_float(v.x << 16); a[1] += __uint_as_float(v.x & 0xffff0000u);
    a[2] += __uint_as_float(v.y << 16); a[3] += __uint_as_float(v.y & 0xffff0000u);
    a[4] += __uint_as_float(v.z << 16); a[5] += __uint_as_float(v.z & 0xffff0000u);
    a[6] += __uint_as_float(v.w << 16); a[7] += __uint_as_float(v.w & 0xffff0000u);
}
__device__ inline void mand(uint4& v, int p) {     // zero the lane's contribution if !p
    unsigned m = p ? 0xffffffffu : 0u;
    v.x &= m; v.y &= m; v.z &= m; v.w &= m;
}
__device__ inline void nt_store16(void* p, uint4 v) {
    u32x4 x; x.x = v.x; x.y = v.y; x.z = v.z; x.w = v.w;
    __builtin_nontemporal_store(x, (u32x4*)p);
}
__device__ inline float4 nt_loadf4(const float* p) {
    fl4 x = __builtin_nontemporal_load((const fl4*)p);
    float4 r; r.x = x.x; r.y = x.y; r.z = x.z; r.w = x.w;
    return r;
}

// ---------- fused prep + sortP1 ----------
#define PZ (GG * DD)                   // 2048 floats (pool) to zero
#define PC (NN * DD / 4)               // 1600000 float4 groups
#define PW (4 * DD * DD)               // 65536 weight elements
#define PTOT (PZ + PC + PW)
#define PBLK ((PTOT + 255) / 256)      // prep blocks

__global__ __launch_bounds__(256) void prepsort_kernel(
    const float* __restrict__ h,
    const float* __restrict__ a, const float* __restrict__ b,
    const float* __restrict__ c, const float* __restrict__ d,
    int* __restrict__ zbase, u16* __restrict__ H0, u16* __restrict__ wt,
    const int* __restrict__ dst, int* __restrict__ counts) {
    __shared__ int hist[NBK];
    int blk = blockIdx.x, t = threadIdx.x;
    if (blk < NBK) {                                 // ---- sortP1 part
        for (int i = t; i < NBK; i += 256) hist[i] = 0;
        __syncthreads();
        int e0 = blk * BCH, e1 = min(e0 + BCH, EE);
        for (int e = e0 + t; e < e1; e += 256) atomicAdd(&hist[dst[e] >> 8], 1);
        __syncthreads();
        for (int i = t; i < NBK; i += 256) counts[i * NBK + blk] = hist[i];  // transposed
        return;
    }
    // ---- prep part
    int i = (blk - NBK) * 256 + t;
    if (i < PZ) { zbase[i] = 0; return; }
    i -= PZ;
    if (i < PC) {
        int j = i * 4;
        float4 v = nt_loadf4(h + j);                 // h read once: don't pollute L2
        ushort4 o;
        o.x = f2bf(v.x); o.y = f2bf(v.y); o.z = f2bf(v.z); o.w = f2bf(v.w);
        *(ushort4*)(H0 + j) = o;
        return;
    }
    i -= PC;
    if (i < PW) {
        int m = i >> 14, r = i & 16383, k = r >> 7, j = r & 127;
        const float* W = (m == 0) ? a : (m == 1) ? b : (m == 2) ? c : d;
        wt[(m << 14) + (j << 7) + k] = f2bf(W[(k << 7) + j]);
    }
}

// ---------- parallel flat exclusive scan of counts_T[FT] (3-phase) ----------
__global__ __launch_bounds__(256) void scanA_kernel(int* __restrict__ counts,
                                                    int* __restrict__ bsum) {
    __shared__ int tmp[256];
    int t = threadIdx.x, idx = blockIdx.x * 256 + t;
    int v = (idx < FT) ? counts[idx] : 0;
    tmp[t] = v; __syncthreads();
    for (int off = 1; off < 256; off <<= 1) {
        int x = (t >= off) ? tmp[t - off] : 0;
        __syncthreads();
        tmp[t] += x;
        __syncthreads();
    }
    if (idx < FT) counts[idx] = tmp[t] - v;          // exclusive within block
    if (t == 255) bsum[blockIdx.x] = tmp[255];
}

__global__ __launch_bounds__(256) void scanB_kernel(int* __restrict__ bsum,
                                                    const int* __restrict__ gids,
                                                    int* __restrict__ gstart) {
    __shared__ int tmp[256];
    int t = threadIdx.x;
    if (t <= GG) {                                  // graph boundary binary search
        int lo = 0, hi = NN;
        while (lo < hi) { int mid = (lo + hi) >> 1; if (gids[mid] < t) lo = mid + 1; else hi = mid; }
        gstart[t] = lo;
    }
    int v = (t < NSCN) ? bsum[t] : 0;
    tmp[t] = v; __syncthreads();
    for (int off = 1; off < 256; off <<= 1) {
        int x = (t >= off) ? tmp[t - off] : 0;
        __syncthreads();
        tmp[t] += x;
        __syncthreads();
    }
    if (t < NSCN) bsum[t] = tmp[t] - v;              // exclusive block offsets
}

__global__ __launch_bounds__(256) void scanC_kernel(int* __restrict__ counts,
                                                    const int* __restrict__ bsum) {
    int idx = blockIdx.x * 256 + threadIdx.x;
    if (idx < FT) counts[idx] += bsum[blockIdx.x];
}

// ---------- sortP3: block-local counting sort -> run-coalesced epack writes ----------
__global__ __launch_bounds__(256) void sortP3_kernel(const int* __restrict__ src,
                                                     const int* __restrict__ dst,
                                                     const int* __restrict__ counts,
                                                     int* __restrict__ epack) {
    __shared__ int lhist[NBK + 1];
    __shared__ int lcur[NBK];
    __shared__ int goff[NBK];
    __shared__ int tmp[256];
    __shared__ int sbuf[BCH];        // locally sorted packed edges (16 KB)
    int b = blockIdx.x, t = threadIdx.x;
    int e0 = b * BCH, e1 = min(e0 + BCH, EE), n = e1 - e0;

    for (int i = t; i < NBK; i += 256) lhist[i] = 0;
    __syncthreads();
    for (int e = e0 + t; e < e1; e += 256) atomicAdd(&lhist[dst[e] >> 8], 1);
    __syncthreads();
    int v = (t < NBK) ? lhist[t] : 0;
    tmp[t] = v; __syncthreads();
    for (int off = 1; off < 256; off <<= 1) {        // inclusive scan of local hist
        int x = (t >= off) ? tmp[t - off] : 0;
        __syncthreads();
        tmp[t] += x;
        __syncthreads();
    }
    if (t < NBK) {
        int excl = tmp[t] - v;
        lcur[t] = excl;
        lhist[t] = excl;
        goff[t] = counts[t * NBK + b] - excl;        // epack dest = goff[j] + local_idx
    }
    if (t == 0) lhist[NBK] = n;
    __syncthreads();
    for (int e = e0 + t; e < e1; e += 256) {         // local scatter into sbuf
        int dd = dst[e], s = src[e];
        int p = atomicAdd(&lcur[dd >> 8], 1);
        sbuf[p] = (s << 8) | (dd & 255);             // src<2^16, local dst 8b
    }
    __syncthreads();
    for (int i = t; i < n; i += 256) {               // coalesced write-out per bucket run
        int pk = sbuf[i];
        int lo = 0, hi = NBK - 1;                    // largest j with lhist[j] <= i
        while (lo < hi) { int mid = (lo + hi + 1) >> 1; if (lhist[mid] <= i) lo = mid; else hi = mid - 1; }
        epack[goff[lo] + i] = pk;
    }
}

// ---------- sortP4 (1 block/bucket): local counting sort; offs + ssrc coalesced ----------
__global__ __launch_bounds__(256) void sortP4_kernel(const int* __restrict__ epack,
                                                     const int* __restrict__ counts,
                                                     int* __restrict__ offs,
                                                     int* __restrict__ ssrc) {
    __shared__ int hist[256];
    __shared__ int curs[256];
    __shared__ int stage[SMAX];
    int j = blockIdx.x, t = threadIdx.x;
    int n0 = j << 8;
    int b0 = counts[j * NBK];                       // bucket base = flat scan at (j,0)
    int b1 = (j < NBK - 1) ? counts[(j + 1) * NBK] : EE;
    hist[t] = 0;
    __syncthreads();
    for (int e = b0 + t; e < b1; e += 256) atomicAdd(&hist[epack[e] & 255], 1);
    __syncthreads();
    int deg = hist[t];
    for (int off = 1; off < 256; off <<= 1) {       // inclusive scan
        int x = (t >= off) ? hist[t - off] : 0;
        __syncthreads();
        hist[t] += x;
        __syncthreads();
    }
    int loff = hist[t] - deg;                       // exclusive local offset
    curs[t] = loff;
    if (n0 + t <= NN) offs[n0 + t] = b0 + loff;     // block 195/t=80 writes offs[NN]=EE
    __syncthreads();
    for (int e = b0 + t; e < b1; e += 256) {
        int pk = epack[e];
        int p = atomicAdd(&curs[pk & 255], 1);
        stage[p] = pk >> 8;                         // src
    }
    __syncthreads();
    int n = b1 - b0;
    for (int i = t; i < n; i += 256) ssrc[b0 + i] = stage[i];   // coalesced
}

// ---------- aggregation: z = h + sum_{incoming} h_src ----------
// work item = FULL node row: 16 lanes x 16B = 256B; 16 items per 256-block.
// One edge-list walk per node (was two with half-row items): index loads,
// loop control, and masking all halve; gathered rows fetched whole.
__global__ __launch_bounds__(256) void agg_kernel(
    const u16* __restrict__ Hin, const int* __restrict__ offs,
    const int* __restrict__ ssrc, u16* __restrict__ Z) {
    int node = blockIdx.x * 16 + (threadIdx.x >> 4);
    int lid = threadIdx.x & 15;
    if (node >= NN) return;
    int foff = lid * 8;                               // 16B slice of the 256B row
    const u16* base = Hin + foff;

    float acc[8] = {0.f, 0.f, 0.f, 0.f, 0.f, 0.f, 0.f, 0.f};
    uint4 vs = *(const uint4*)(base + (size_t)node * DD);
    int e0 = offs[node], e1 = offs[node + 1];
    acc8(acc, vs);                                    // self term (eps=0)

    int nch = (e1 - e0 + 7) >> 3;
    if (nch > 0) {
        int elast = e1 - 1;
        int i0 = ssrc[e0];
        int i1 = ssrc[min(e0 + 1, elast)];
        int i2 = ssrc[min(e0 + 2, elast)];
        int i3 = ssrc[min(e0 + 3, elast)];
        int i4 = ssrc[min(e0 + 4, elast)];
        int i5 = ssrc[min(e0 + 5, elast)];
        int i6 = ssrc[min(e0 + 6, elast)];
        int i7 = ssrc[min(e0 + 7, elast)];
        int eb = e0;
        for (int c = 0; c < nch; c++) {
            int ebn = eb + 8;
            int n0 = i0, n1 = i1, n2 = i2, n3 = i3, n4 = i4, n5 = i5, n6 = i6, n7 = i7;
            if (c + 1 < nch) {                         // prefetch next chunk indices
                n0 = ssrc[ebn];
                n1 = ssrc[min(ebn + 1, elast)];
                n2 = ssrc[min(ebn + 2, elast)];
                n3 = ssrc[min(ebn + 3, elast)];
                n4 = ssrc[min(ebn + 4, elast)];
                n5 = ssrc[min(ebn + 5, elast)];
                n6 = ssrc[min(ebn + 6, elast)];
                n7 = ssrc[min(ebn + 7, elast)];
            }
            uint4 v0 = *(const uint4*)(base + (size_t)i0 * DD);
            uint4 v1 = *(const uint4*)(base + (size_t)i1 * DD);
            uint4 v2 = *(const uint4*)(base + (size_t)i2 * DD);
            uint4 v3 = *(const uint4*)(base + (size_t)i3 * DD);
            uint4 v4 = *(const uint4*)(base + (size_t)i4 * DD);
            uint4 v5 = *(const uint4*)(base + (size_t)i5 * DD);
            uint4 v6 = *(const uint4*)(base + (size_t)i6 * DD);
            uint4 v7 = *(const uint4*)(base + (size_t)i7 * DD);
            mand(v1, eb + 1 < e1); mand(v2, eb + 2 < e1); mand(v3, eb + 3 < e1);
            mand(v4, eb + 4 < e1); mand(v5, eb + 5 < e1); mand(v6, eb + 6 < e1);
            mand(v7, eb + 7 < e1);                     // slot 0 always valid
            acc8(acc, v0); acc8(acc, v1); acc8(acc, v2); acc8(acc, v3);
            acc8(acc, v4); acc8(acc, v5); acc8(acc, v6); acc8(acc, v7);
            i0 = n0; i1 = n1; i2 = n2; i3 = n3; i4 = n4; i5 = n5; i6 = n6; i7 = n7;
            eb = ebn;
        }
    }
    uint4 o;
    o.x = pack2(acc[0], acc[1]); o.y = pack2(acc[2], acc[3]);
    o.z = pack2(acc[4], acc[5]); o.w = pack2(acc[6], acc[7]);
    nt_store16(Z + (size_t)node * DD + foff, o);      // stream-once: keep L2 for gathers
}

// ---------- MLP v2: persistent blocks, W1 in LDS (fragment-ordered), W2 in regs ----------
__global__ __launch_bounds__(256, 1) void mlp_kernel(
    const u16* __restrict__ Zin, const u16* __restrict__ Wt1, const float* __restrict__ b1,
    const u16* __restrict__ Wt2, const float* __restrict__ b2,
    u16* __restrict__ Hout, const int* __restrict__ gids, float* __restrict__ pool) {
    __shared__ __align__(16) u16 w1f[16384];   // 32KB fragment-ordered W1
    __shared__ __align__(16) u16 yb[64][136];  // 17.4KB transpose staging
    const int tid = threadIdx.x;
    const int wave = tid >> 6;
    const int lane = tid & 63;
    const int m16 = lane & 15;
    const int quad = lane >> 4;

    // stage W1 fragment-ordered: chunk c -> (kk=c>>9, nt=(c>>6)&7, lane=c&63)
    for (int cidx = tid; cidx < 2048; cidx += 256) {
        int ln = cidx & 63, nt = (cidx >> 6) & 7, kk = cidx >> 9;
        int gofs = ((nt * 16 + (ln & 15)) << 7) + kk * 32 + (ln >> 4) * 8;
        *(uint4*)&w1f[cidx * 8] = *(const uint4*)(Wt1 + gofs);
    }
    // W2 fragments -> registers (loaded once, reused for all tiles)
    bf16x8 w2r[4][8];
#pragma unroll
    for (int kk = 0; kk < 4; kk++)
#pragma unroll
        for (int nt = 0; nt < 8; nt++)
            w2r[kk][nt] = *(const bf16x8*)(Wt2 + ((nt * 16 + m16) << 7) + kk * 32 + quad * 8);
    // biases hoisted
    float bias1[8], bias2[8];
#pragma unroll
    for (int nt = 0; nt < 8; nt++) {
        bias1[nt] = b1[nt * 16 + m16];
        bias2[nt] = b2[nt * 16 + m16];
    }
    __syncthreads();

    int tile = blockIdx.x;
    bf16x8 afr[4], afrN[4];
    {
        size_t row = (size_t)(tile * 64 + wave * 16 + m16);
#pragma unroll
        for (int kk = 0; kk < 4; kk++)
            afr[kk] = *(const bf16x8*)(Zin + row * DD + kk * 32 + quad * 8);
    }
    for (; tile < NT; tile += 256) {
        int nxt = tile + 256;
        if (nxt < NT) {                              // prefetch next tile's A-fragments
            size_t row = (size_t)(nxt * 64 + wave * 16 + m16);
#pragma unroll
            for (int kk = 0; kk < 4; kk++)
                afrN[kk] = *(const bf16x8*)(Zin + row * DD + kk * 32 + quad * 8);
        }
        const int row0 = tile * 64 + wave * 16;

        // ---- GEMM1 (B from LDS, conflict-free fragment order)
        f32x4 acc[8];
#pragma unroll
        for (int nt = 0; nt < 8; nt++) acc[nt] = (f32x4){0.f, 0.f, 0.f, 0.f};
#pragma unroll
        for (int kk = 0; kk < 4; kk++) {
#pragma unroll
            for (int nt = 0; nt < 8; nt++) {
                bf16x8 bfr = *(const bf16x8*)&w1f[(((kk * 8 + nt) * 64) + lane) * 8];
                acc[nt] = __builtin_amdgcn_mfma_f32_16x16x32_bf16(afr[kk], bfr, acc[nt], 0, 0, 0);
            }
        }
#pragma unroll
        for (int nt = 0; nt < 8; nt++) {             // y -> yb (wave-private)
            int col = nt * 16 + m16;
#pragma unroll
            for (int r = 0; r < 4; r++) {
                float yv = acc[nt][r] + bias1[nt];
                yv = yv > 0.f ? yv : 0.f;
                yb[wave * 16 + quad * 4 + r][col] = f2bf(yv);
            }
        }

        // ---- GEMM2 (B entirely in registers — zero loads)
        bf16x8 afr2[4];
#pragma unroll
        for (int kk = 0; kk < 4; kk++)
            afr2[kk] = *(const bf16x8*)&yb[wave * 16 + m16][kk * 32 + quad * 8];
#pragma unroll
        for (int nt = 0; nt < 8; nt++) acc[nt] = (f32x4){0.f, 0.f, 0.f, 0.f};
#pragma unroll
        for (int kk = 0; kk < 4; kk++) {
#pragma unroll
            for (int nt = 0; nt < 8; nt++)
                acc[nt] = __builtin_amdgcn_mfma_f32_16x16x32_bf16(afr2[kk], w2r[kk][nt], acc[nt], 0, 0, 0);
        }
#pragma unroll
        for (int nt = 0; nt < 8; nt++) {             // out -> yb
            int col = nt * 16 + m16;
#pragma unroll
            for (int r = 0; r < 4; r++) {
                float ov = acc[nt][r] + bias2[nt];
                ov = ov > 0.f ? ov : 0.f;
                yb[wave * 16 + quad * 4 + r][col] = f2bf(ov);
            }
        }
        if (!pool) {                                 // layer 1: store H (cached; agg2 gathers it)
#pragma unroll
            for (int p = 0; p < 4; p++) {
                int idx = p * 64 + lane;
                int r = idx >> 4, ch = idx & 15;
                int grow = row0 + r;
                if (grow < NN)
                    *(uint4*)(Hout + (size_t)grow * DD + ch * 8) = *(const uint4*)&yb[wave * 16 + r][ch * 8];
            }
        } else {                                     // layer 2: fused mean-pool, no H store
            int prow = row0 + m16;
            int g = gids[min(prow, NN - 1)];
#pragma unroll
            for (int fsel = 0; fsel < 2; fsel++) {
                int f = lane + fsel * 64;
                float s = 0.f;
                int cur = __shfl(g, 0);
                for (int r = 0; r < 16; r++) {
                    int gr = __shfl(g, r);
                    float v = (row0 + r < NN) ? bf2f((unsigned)yb[wave * 16 + r][f]) : 0.f;
                    if (gr != cur) { atomicAdd(&pool[cur * DD + f], s); s = 0.f; cur = gr; }
                    s += v;
                }
                atomicAdd(&pool[cur * DD + f], s);
            }
        }
#pragma unroll
        for (int kk = 0; kk < 4; kk++) afr[kk] = afrN[kk];   // rotate prefetch
    }
}

// ---------- classifier (fp32) ----------
__global__ void cls_kernel(const float* __restrict__ pool, const int* __restrict__ gstart,
                           const float* __restrict__ Wc1, const float* __restrict__ bc1,
                           const float* __restrict__ Wc2, const float* __restrict__ bc2,
                           float* __restrict__ out) {
    __shared__ float hg[128];
    __shared__ float y1[128];
    int g = blockIdx.x;
    int t = threadIdx.x;   // 128 threads
    int cnt = gstart[g + 1] - gstart[g];
    float inv = 1.f / (float)(cnt > 1 ? cnt : 1);
    hg[t] = pool[g * DD + t] * inv;
    __syncthreads();
    float a = bc1[t];
    for (int k = 0; k < DD; k++) a += hg[k] * Wc1[k * DD + t];
    y1[t] = a > 0.f ? a : 0.f;
    __syncthreads();
    if (t < CC) {
        float o = bc2[t];
        for (int k = 0; k < DD; k++) o += y1[k] * Wc2[k * CC + t];
        out[g * CC + t] = o;
    }
}

extern "C" void kernel_launch(void* const* d_in, const int* in_sizes, int n_in,
                              void* d_out, int out_size, void* d_ws, size_t ws_size,
                              hipStream_t stream) {
    const float* h    = (const float*)d_in[0];
    const int*   src  = (const int*)d_in[1];
    const int*   dst  = (const int*)d_in[2];
    const int*   gids = (const int*)d_in[3];
    const float* W1a  = (const float*)d_in[4];
    const float* b1a  = (const float*)d_in[5];
    const float* W2a  = (const float*)d_in[6];
    const float* b2a  = (const float*)d_in[7];
    const float* W1b  = (const float*)d_in[8];
    const float* b1b  = (const float*)d_in[9];
    const float* W2b  = (const float*)d_in[10];
    const float* b2b  = (const float*)d_in[11];
    const float* Wc1  = (const float*)d_in[12];
    const float* bc1  = (const float*)d_in[13];
    const float* Wc2  = (const float*)d_in[14];
    const float* bc2  = (const float*)d_in[15];
    float* out = (float*)d_out;

    char* ws = (char*)d_ws;
    u16*   H0     = (u16*)(ws);                    // 12,800,000 B
    u16*   H1     = (u16*)(ws + 12800000);         // 12,800,000 B
    u16*   H2     = (u16*)(ws + 25600000);         // 12,800,000 B
    u16*   Wt     = (u16*)(ws + 38400000);         // 131,072 B
    float* pool   = (float*)(ws + 38531072);       // 8,192 B (zeroed by prep)
    int*   offs   = (int*)(ws + 38539264);         // 200,004 B
    int*   ssrc   = (int*)(ws + 38739268);         // 3,200,000 B
    int*   gstart = (int*)(ws + 41939268);         // 68 B
    int*   counts = (int*)(ws + 41939336);         // 153,664 B (196x196, transposed)
    int*   bsum   = (int*)(ws + 42093000);         // 604 B (scan block sums)
    int*   epack  = (int*)(ws + 42093792);         // 3,200,000 B (packed src|dstlocal)
    u16*   Z1     = H2;                            // scratch z, layer 1 (H2 unused otherwise)
    u16*   Z2     = H0;                            // scratch z, layer 2 (H0 dead after agg1)

    prepsort_kernel<<<dim3(NBK + PBLK), dim3(256), 0, stream>>>(
        h, W1a, W2a, W1b, W2b, (int*)pool, H0, Wt, dst, counts);
    scanA_kernel<<<dim3(NSCN), dim3(256), 0, stream>>>(counts, bsum);
    scanB_kernel<<<dim3(1), dim3(256), 0, stream>>>(bsum, gids, gstart);
    scanC_kernel<<<dim3(NSCN), dim3(256), 0, stream>>>(counts, bsum);
    sortP3_kernel<<<dim3(NBK), dim3(256), 0, stream>>>(src, dst, counts, epack);
    sortP4_kernel<<<dim3(NBK), dim3(256), 0, stream>>>(epack, counts, offs, ssrc);
    agg_kernel<<<dim3((NN + 15) / 16), dim3(256), 0, stream>>>(H0, offs, ssrc, Z1);
    mlp_kernel<<<dim3(256), dim3(256), 0, stream>>>(Z1, Wt, b1a, Wt + 16384, b2a, H1, gids, nullptr);
    agg_kernel<<<dim3((NN + 15) / 16), dim3(256), 0, stream>>>(H1, offs, ssrc, Z2);
    mlp_kernel<<<dim3(256), dim3(256), 0, stream>>>(Z2, Wt + 32768, b1b, Wt + 49152, b2b, H2, gids, pool);
    cls_kernel<<<dim3(GG), dim3(128), 0, stream>>>(pool, gstart, Wc1, bc1, Wc2, bc2, out);
}